// Round 1
// baseline (677.532 us; speedup 1.0000x reference)
//
#include <hip/hip_runtime.h>
#include <math.h>

#define N_SEQ 1024
#define T_SEQ 64
#define DIMX  32
#define LDIM  256
#define NAUX  128
#define AUXH  128
#define ENCH  256
#define OUTC  288           // DIMX + LDIM
#define DT    0.01f

// 4x4 outer-product accumulate: ACC[ni][ji] += XV[ni] * WV[ji]
#define OP16(ACC, XV, WV) do { \
  ACC[0][0] += XV.x*WV.x; ACC[0][1] += XV.x*WV.y; ACC[0][2] += XV.x*WV.z; ACC[0][3] += XV.x*WV.w; \
  ACC[1][0] += XV.y*WV.x; ACC[1][1] += XV.y*WV.y; ACC[1][2] += XV.y*WV.z; ACC[1][3] += XV.y*WV.w; \
  ACC[2][0] += XV.z*WV.x; ACC[2][1] += XV.z*WV.y; ACC[2][2] += XV.z*WV.z; ACC[2][3] += XV.z*WV.w; \
  ACC[3][0] += XV.w*WV.x; ACC[3][1] += XV.w*WV.y; ACC[3][2] += XV.w*WV.z; ACC[3][3] += XV.w*WV.w; \
} while (0)

// ---------------------------------------------------------------------------
// K1: aux MLPs. One block = one aux-net k  x  32 n's.
// h1 = relu(x0 @ W1k + b1k); h2 = relu(h1 @ W2k + b2k); aux = h2 @ W3k
// stores a = aux0*DT, th = aux1*DT  into workspace.
// ---------------------------------------------------------------------------
__global__ __launch_bounds__(256) void aux_kernel(
    const float* __restrict__ xs,
    const float* __restrict__ W1, const float* __restrict__ b1,
    const float* __restrict__ W2, const float* __restrict__ b2,
    const float* __restrict__ W3,
    float* __restrict__ a_ws, float* __restrict__ th_ws)
{
    const int k   = blockIdx.x >> 5;          // aux net index (128)
    const int n0  = (blockIdx.x & 31) << 5;   // first of 32 n's
    const int tid = threadIdx.x;
    const int jg  = tid & 31;                 // j tile: jg*4 .. +3   (128 cols)
    const int ng  = tid >> 5;                 // n tile: ng*4 .. +3   (32 rows)

    __shared__ float x0s[32][36];   // [d][n_l]   (pad 36: 16B-aligned rows)
    __shared__ float h1s[128][36];  // [h][n_l]
    __shared__ float h2s[32][132];  // [n_l][j]

    // stage x0 (transposed): coalesced global read along d
    for (int i = tid; i < 32 * 32; i += 256) {
        int n_l = i >> 5, d = i & 31;
        x0s[d][n_l] = xs[(size_t)(n0 + n_l) * (T_SEQ * DIMX) + d];
    }
    __syncthreads();

    // ---- layer 1: (32n x 32d) @ (32d x 128j) ----
    const float* W1k = W1 + (size_t)k * 32 * 128;
    float acc[4][4];
    #pragma unroll
    for (int a = 0; a < 4; ++a)
        #pragma unroll
        for (int b = 0; b < 4; ++b) acc[a][b] = 0.f;

    #pragma unroll 8
    for (int d = 0; d < 32; ++d) {
        float4 xv = *(const float4*)&x0s[d][ng * 4];
        float4 wv = *(const float4*)&W1k[d * 128 + jg * 4];
        OP16(acc, xv, wv);
    }
    {
        float4 b1v = *(const float4*)&b1[k * 128 + jg * 4];
        float bb[4] = {b1v.x, b1v.y, b1v.z, b1v.w};
        #pragma unroll
        for (int ji = 0; ji < 4; ++ji)
            #pragma unroll
            for (int ni = 0; ni < 4; ++ni)
                h1s[jg * 4 + ji][ng * 4 + ni] = fmaxf(acc[ni][ji] + bb[ji], 0.f);
    }
    __syncthreads();

    // ---- layer 2: (32n x 128h) @ (128h x 128j) ----
    const float* W2k = W2 + (size_t)k * 128 * 128;
    #pragma unroll
    for (int a = 0; a < 4; ++a)
        #pragma unroll
        for (int b = 0; b < 4; ++b) acc[a][b] = 0.f;

    #pragma unroll 4
    for (int h = 0; h < 128; ++h) {
        float4 hv = *(const float4*)&h1s[h][ng * 4];
        float4 wv = *(const float4*)&W2k[h * 128 + jg * 4];
        OP16(acc, hv, wv);
    }
    {
        float4 b2v = *(const float4*)&b2[k * 128 + jg * 4];
        float bb[4] = {b2v.x, b2v.y, b2v.z, b2v.w};
        #pragma unroll
        for (int ji = 0; ji < 4; ++ji)
            #pragma unroll
            for (int ni = 0; ni < 4; ++ni)
                h2s[ng * 4 + ni][jg * 4 + ji] = fmaxf(acc[ni][ji] + bb[ji], 0.f);
    }
    __syncthreads();

    // ---- layer 3: aux[n][o] = sum_j h2[n][j] * W3k[j][o],  o in {0,1} ----
    if (tid < 32) {
        const float* W3k = W3 + (size_t)k * (AUXH * 2);
        float s0 = 0.f, s1 = 0.f;
        #pragma unroll 8
        for (int j = 0; j < 128; j += 4) {
            float4 hv = *(const float4*)&h2s[tid][j];
            float4 wa = *(const float4*)&W3k[j * 2];
            float4 wb = *(const float4*)&W3k[j * 2 + 4];
            s0 += hv.x * wa.x + hv.y * wa.z + hv.z * wb.x + hv.w * wb.z;
            s1 += hv.x * wa.y + hv.y * wa.w + hv.z * wb.y + hv.w * wb.w;
        }
        const int n = n0 + tid;
        a_ws [n * NAUX + k] = s0 * DT;
        th_ws[n * NAUX + k] = s1 * DT;
    }
}

// ---------------------------------------------------------------------------
// K2: encoder MLP on all N*T rows. One block = 64 rows, thread = one column.
// e = relu(X@W1+b1); e = relu(e@W2+b2); e = e@W3.
// Writes y = concat([xs, e], -1) directly (first output).
// ---------------------------------------------------------------------------
__global__ __launch_bounds__(256) void enc_kernel(
    const float* __restrict__ xs,
    const float* __restrict__ W1, const float* __restrict__ b1,
    const float* __restrict__ W2, const float* __restrict__ b2,
    const float* __restrict__ W3,
    float* __restrict__ y)
{
    __shared__ float Xs[64 * 32];    // 8 KB
    __shared__ float Hs[64 * 256];   // 64 KB
    const int tid  = threadIdx.x;
    const int c    = tid;            // column 0..255
    const int row0 = blockIdx.x * 64;

    // stage X tile (64 rows x 32) — contiguous, float4
    {
        const float4* src = (const float4*)(xs + (size_t)row0 * DIMX);
        float4* dst = (float4*)Xs;
        dst[tid]       = src[tid];
        dst[tid + 256] = src[tid + 256];
    }
    __syncthreads();

    float acc[64];

    // ---- layer 1 (K=32) ----
    {
        float w[32];
        #pragma unroll
        for (int d = 0; d < 32; ++d) w[d] = W1[d * ENCH + c];
        const float bb = b1[c];
        #pragma unroll
        for (int r = 0; r < 64; ++r) {
            float a = bb;
            #pragma unroll
            for (int d4 = 0; d4 < 8; ++d4) {
                float4 xv = *(const float4*)&Xs[r * 32 + d4 * 4];
                a += xv.x * w[d4 * 4] + xv.y * w[d4 * 4 + 1]
                   + xv.z * w[d4 * 4 + 2] + xv.w * w[d4 * 4 + 3];
            }
            acc[r] = a;
        }
        #pragma unroll
        for (int r = 0; r < 64; ++r) Hs[r * 256 + c] = fmaxf(acc[r], 0.f);
    }
    __syncthreads();

    // ---- layer 2 (K=256) ----
    {
        const float bb = b2[c];
        #pragma unroll
        for (int r = 0; r < 64; ++r) acc[r] = bb;
        for (int hc = 0; hc < 8; ++hc) {
            float w[32];
            #pragma unroll
            for (int i = 0; i < 32; ++i) w[i] = W2[(hc * 32 + i) * ENCH + c];
            #pragma unroll
            for (int r = 0; r < 64; ++r) {
                float a = acc[r];
                #pragma unroll
                for (int h4 = 0; h4 < 8; ++h4) {
                    float4 hv = *(const float4*)&Hs[r * 256 + hc * 32 + h4 * 4];
                    a += hv.x * w[h4 * 4] + hv.y * w[h4 * 4 + 1]
                       + hv.z * w[h4 * 4 + 2] + hv.w * w[h4 * 4 + 3];
                }
                acc[r] = a;
            }
        }
        __syncthreads();   // all reads of Hs done
        #pragma unroll
        for (int r = 0; r < 64; ++r) Hs[r * 256 + c] = fmaxf(acc[r], 0.f);
    }
    __syncthreads();

    // ---- layer 3 (K=256, no bias/relu) ----
    {
        #pragma unroll
        for (int r = 0; r < 64; ++r) acc[r] = 0.f;
        for (int hc = 0; hc < 8; ++hc) {
            float w[32];
            #pragma unroll
            for (int i = 0; i < 32; ++i) w[i] = W3[(hc * 32 + i) * LDIM + c];
            #pragma unroll
            for (int r = 0; r < 64; ++r) {
                float a = acc[r];
                #pragma unroll
                for (int h4 = 0; h4 < 8; ++h4) {
                    float4 hv = *(const float4*)&Hs[r * 256 + hc * 32 + h4 * 4];
                    a += hv.x * w[h4 * 4] + hv.y * w[h4 * 4 + 1]
                       + hv.z * w[h4 * 4 + 2] + hv.w * w[h4 * 4 + 3];
                }
                acc[r] = a;
            }
        }
    }

    // write e into y[.., 32:288]
    #pragma unroll
    for (int r = 0; r < 64; ++r)
        y[(size_t)(row0 + r) * OUTC + DIMX + c] = acc[r];

    // write xs into y[.., 0:32]
    for (int i = tid; i < 64 * 32; i += 256) {
        int r = i >> 5, d = i & 31;
        y[(size_t)(row0 + r) * OUTC + d] = Xs[r * 32 + d];
    }
}

// ---------------------------------------------------------------------------
// K3: closed-form scan + readout. block = (n, 8 t's), thread = latent element.
// ys[t] = exp(a*t) * cis(th*t) applied to y0 pairs (z^t, exact closed form).
// Writes y_pred (second output): [0:32]=x_pred, [32:288]=y_lat.
// ---------------------------------------------------------------------------
__global__ __launch_bounds__(256) void scan_kernel(
    const float* __restrict__ xs,
    const float* __restrict__ a_ws, const float* __restrict__ th_ws,
    const float* __restrict__ C_W,
    const float* __restrict__ y,    // first output (holds e)
    float* __restrict__ yp)         // second output
{
    const int n   = blockIdx.x >> 3;
    const int tg  = blockIdx.x & 7;       // t tile: tg*8 .. +7
    const int tid = threadIdx.x;           // latent element 0..255
    const int k   = tid >> 1;              // pair index

    __shared__ float ys_lds[8][256];

    // y0 pair from e[:,0,:] (already in y)
    const float* yrow0 = y + (size_t)n * T_SEQ * OUTC + DIMX;
    float2 y0 = *(const float2*)&yrow0[tid & ~1];
    const float a  = a_ws [n * NAUX + k];
    const float th = th_ws[n * NAUX + k];

    float* ypn = yp + (size_t)n * T_SEQ * OUTC;

    #pragma unroll
    for (int tt = 0; tt < 8; ++tt) {
        const int t = tg * 8 + tt;
        float val;
        if (t == 0) {
            val = (tid & 1) ? y0.y : y0.x;
        } else {
            const float tf = (float)t;
            const float m  = expf(a * tf);
            float ss, sc;
            sincosf(th * tf, &ss, &sc);
            const float v1 = m * (y0.x * sc - y0.y * ss);
            const float v2 = m * (y0.x * ss + y0.y * sc);
            val = (tid & 1) ? v2 : v1;
        }
        ypn[(size_t)t * OUTC + DIMX + tid] = val;   // y_lat
        ys_lds[tt][tid] = val;
    }
    __syncthreads();

    // x_pred: (8t x 32) = ys_tile @ C_W   (thread = one output)
    const int tt = tid >> 5, d = tid & 31;
    const int t  = tg * 8 + tt;
    float o;
    if (t == 0) {
        o = xs[(size_t)n * T_SEQ * DIMX + d];
    } else {
        float s = 0.f;
        #pragma unroll 8
        for (int l = 0; l < 256; l += 4) {
            float4 yv = *(const float4*)&ys_lds[tt][l];
            s += yv.x * C_W[(l    ) * DIMX + d]
               + yv.y * C_W[(l + 1) * DIMX + d]
               + yv.z * C_W[(l + 2) * DIMX + d]
               + yv.w * C_W[(l + 3) * DIMX + d];
        }
        o = s;
    }
    ypn[(size_t)t * OUTC + d] = o;
}

// ---------------------------------------------------------------------------
extern "C" void kernel_launch(void* const* d_in, const int* in_sizes, int n_in,
                              void* d_out, int out_size, void* d_ws, size_t ws_size,
                              hipStream_t stream)
{
    const float* xs   = (const float*)d_in[0];
    const float* eW1  = (const float*)d_in[1];
    const float* eb1  = (const float*)d_in[2];
    const float* eW2  = (const float*)d_in[3];
    const float* eb2  = (const float*)d_in[4];
    const float* eW3  = (const float*)d_in[5];
    const float* aW1  = (const float*)d_in[6];
    const float* ab1  = (const float*)d_in[7];
    const float* aW2  = (const float*)d_in[8];
    const float* ab2  = (const float*)d_in[9];
    const float* aW3  = (const float*)d_in[10];
    const float* C_W  = (const float*)d_in[11];

    float* y  = (float*)d_out;
    float* yp = y + (size_t)N_SEQ * T_SEQ * OUTC;

    float* a_ws  = (float*)d_ws;
    float* th_ws = a_ws + (size_t)N_SEQ * NAUX;

    aux_kernel <<<128 * 32, 256, 0, stream>>>(xs, aW1, ab1, aW2, ab2, aW3, a_ws, th_ws);
    enc_kernel <<<N_SEQ * T_SEQ / 64, 256, 0, stream>>>(xs, eW1, eb1, eW2, eb2, eW3, y);
    scan_kernel<<<N_SEQ * 8, 256, 0, stream>>>(xs, a_ws, th_ws, C_W, y, yp);
}

// Round 2
// 245.114 us; speedup vs baseline: 2.7641x; 2.7641x over previous
//
#include <hip/hip_runtime.h>
#include <math.h>

#define N_SEQ 1024
#define T_SEQ 64
#define DIMX  32
#define LDIM  256
#define NAUX  128
#define AUXH  128
#define ENCH  256
#define OUTC  288           // DIMX + LDIM
#define DT    0.01f

typedef short bf16x8 __attribute__((ext_vector_type(8)));
typedef float f32x4  __attribute__((ext_vector_type(4)));

__device__ __forceinline__ unsigned short f2bf(float f) {
    unsigned u = __builtin_bit_cast(unsigned, f);
    unsigned r = u + 0x7fffu + ((u >> 16) & 1u);   // RNE
    return (unsigned short)(r >> 16);
}

__device__ __forceinline__ f32x4 mfma16(bf16x8 a, bf16x8 b, f32x4 c) {
    return __builtin_amdgcn_mfma_f32_16x16x32_bf16(a, b, c, 0, 0, 0);
}

// 4x4 outer-product accumulate: ACC[ni][ji] += XV[ni] * WV[ji]
#define OP16(ACC, XV, WV) do { \
  ACC[0][0] += XV.x*WV.x; ACC[0][1] += XV.x*WV.y; ACC[0][2] += XV.x*WV.z; ACC[0][3] += XV.x*WV.w; \
  ACC[1][0] += XV.y*WV.x; ACC[1][1] += XV.y*WV.y; ACC[1][2] += XV.y*WV.z; ACC[1][3] += XV.y*WV.w; \
  ACC[2][0] += XV.z*WV.x; ACC[2][1] += XV.z*WV.y; ACC[2][2] += XV.z*WV.z; ACC[2][3] += XV.z*WV.w; \
  ACC[3][0] += XV.w*WV.x; ACC[3][1] += XV.w*WV.y; ACC[3][2] += XV.w*WV.z; ACC[3][3] += XV.w*WV.w; \
} while (0)

// ---------------------------------------------------------------------------
// K0: convert encoder weights to bf16, TRANSPOSED to [col][k] for B-fragments.
// ---------------------------------------------------------------------------
__global__ __launch_bounds__(256) void convw_kernel(
    const float* __restrict__ W1, const float* __restrict__ W2,
    const float* __restrict__ W3, unsigned short* __restrict__ wt)
{
    const int idx = blockIdx.x * 256 + threadIdx.x;
    if (idx < 8192) {                       // W1T: [256 cols][32 k]
        int c = idx >> 5, k = idx & 31;
        wt[idx] = f2bf(W1[k * ENCH + c]);
    } else if (idx < 8192 + 65536) {        // W2T: [256][256]
        int t = idx - 8192; int c = t >> 8, k = t & 255;
        wt[idx] = f2bf(W2[k * ENCH + c]);
    } else if (idx < 8192 + 131072) {       // W3T: [256][256]
        int t = idx - (8192 + 65536); int c = t >> 8, k = t & 255;
        wt[idx] = f2bf(W3[k * LDIM + c]);
    }
}

// ---------------------------------------------------------------------------
// K1: aux MLPs (fp32 — its outputs are amplified by ~exp(a*0.63)*y*t, must
// stay accurate). One block = one aux-net k x 32 n's.
// ---------------------------------------------------------------------------
__global__ __launch_bounds__(256) void aux_kernel(
    const float* __restrict__ xs,
    const float* __restrict__ W1, const float* __restrict__ b1,
    const float* __restrict__ W2, const float* __restrict__ b2,
    const float* __restrict__ W3,
    float* __restrict__ a_ws, float* __restrict__ th_ws)
{
    const int k   = blockIdx.x >> 5;
    const int n0  = (blockIdx.x & 31) << 5;
    const int tid = threadIdx.x;
    const int jg  = tid & 31;
    const int ng  = tid >> 5;

    __shared__ float x0s[32][36];
    __shared__ float h1s[128][36];
    __shared__ float h2s[32][132];

    for (int i = tid; i < 32 * 32; i += 256) {
        int n_l = i >> 5, d = i & 31;
        x0s[d][n_l] = xs[(size_t)(n0 + n_l) * (T_SEQ * DIMX) + d];
    }
    __syncthreads();

    const float* W1k = W1 + (size_t)k * 32 * 128;
    float acc[4][4];
    #pragma unroll
    for (int a = 0; a < 4; ++a)
        #pragma unroll
        for (int b = 0; b < 4; ++b) acc[a][b] = 0.f;

    #pragma unroll 8
    for (int d = 0; d < 32; ++d) {
        float4 xv = *(const float4*)&x0s[d][ng * 4];
        float4 wv = *(const float4*)&W1k[d * 128 + jg * 4];
        OP16(acc, xv, wv);
    }
    {
        float4 b1v = *(const float4*)&b1[k * 128 + jg * 4];
        float bb[4] = {b1v.x, b1v.y, b1v.z, b1v.w};
        #pragma unroll
        for (int ji = 0; ji < 4; ++ji)
            #pragma unroll
            for (int ni = 0; ni < 4; ++ni)
                h1s[jg * 4 + ji][ng * 4 + ni] = fmaxf(acc[ni][ji] + bb[ji], 0.f);
    }
    __syncthreads();

    const float* W2k = W2 + (size_t)k * 128 * 128;
    #pragma unroll
    for (int a = 0; a < 4; ++a)
        #pragma unroll
        for (int b = 0; b < 4; ++b) acc[a][b] = 0.f;

    #pragma unroll 4
    for (int h = 0; h < 128; ++h) {
        float4 hv = *(const float4*)&h1s[h][ng * 4];
        float4 wv = *(const float4*)&W2k[h * 128 + jg * 4];
        OP16(acc, hv, wv);
    }
    {
        float4 b2v = *(const float4*)&b2[k * 128 + jg * 4];
        float bb[4] = {b2v.x, b2v.y, b2v.z, b2v.w};
        #pragma unroll
        for (int ji = 0; ji < 4; ++ji)
            #pragma unroll
            for (int ni = 0; ni < 4; ++ni)
                h2s[ng * 4 + ni][jg * 4 + ji] = fmaxf(acc[ni][ji] + bb[ji], 0.f);
    }
    __syncthreads();

    if (tid < 32) {
        const float* W3k = W3 + (size_t)k * (AUXH * 2);
        float s0 = 0.f, s1 = 0.f;
        #pragma unroll 8
        for (int j = 0; j < 128; j += 4) {
            float4 hv = *(const float4*)&h2s[tid][j];
            float4 wa = *(const float4*)&W3k[j * 2];
            float4 wb = *(const float4*)&W3k[j * 2 + 4];
            s0 += hv.x * wa.x + hv.y * wa.z + hv.z * wb.x + hv.w * wb.z;
            s1 += hv.x * wa.y + hv.y * wa.w + hv.z * wb.y + hv.w * wb.w;
        }
        const int n = n0 + tid;
        a_ws [n * NAUX + k] = s0 * DT;
        th_ws[n * NAUX + k] = s1 * DT;
    }
}

// ---------------------------------------------------------------------------
// K2: encoder via bf16 MFMA. Block = 64 rows x 256 cols, 4 waves.
// Wave w owns col block w*64..+63. A from LDS (padded), B from global (L2).
// Writes y = concat([xs, e], -1).
// ---------------------------------------------------------------------------
__global__ __launch_bounds__(256) void encm_kernel(
    const float* __restrict__ xs,
    const unsigned short* __restrict__ W1T, const float* __restrict__ b1,
    const unsigned short* __restrict__ W2T, const float* __restrict__ b2,
    const unsigned short* __restrict__ W3T,
    float* __restrict__ y)
{
    __shared__ float          Xf[64 * 36];          // fp32 X tile, +16B pad
    __shared__ unsigned short Hs[64 * 264];         // bf16 H tile, +16B pad

    const int tid = threadIdx.x;
    const int wv  = tid >> 6;
    const int ln  = tid & 63;
    const int lr  = ln & 15;       // row (A) / col (B/D) within 16-tile
    const int g   = ln >> 4;       // k-group (8 elems) / D row-group (4 rows)
    const int cb  = wv * 64;
    const size_t row0 = (size_t)blockIdx.x * 64;

    // stage X (contiguous 8 KB)
    {
        const float4* src = (const float4*)(xs + row0 * DIMX);
        for (int i = tid; i < 512; i += 256) {
            int r = i >> 3, q = i & 7;
            *(float4*)&Xf[r * 36 + q * 4] = src[i];
        }
    }
    __syncthreads();

    // ---- layer 1: K=32, one MFMA step ----
    {
        f32x4 acc[4][4];
        bf16x8 bfr[4], afr[4];
        #pragma unroll
        for (int ct = 0; ct < 4; ++ct)
            bfr[ct] = *(const bf16x8*)&W1T[(cb + ct * 16 + lr) * 32 + g * 8];
        #pragma unroll
        for (int rt = 0; rt < 4; ++rt) {
            const float* xp = &Xf[(rt * 16 + lr) * 36 + g * 8];
            float4 u = *(const float4*)xp;
            float4 v = *(const float4*)(xp + 4);
            bf16x8 t;
            t[0]=(short)f2bf(u.x); t[1]=(short)f2bf(u.y); t[2]=(short)f2bf(u.z); t[3]=(short)f2bf(u.w);
            t[4]=(short)f2bf(v.x); t[5]=(short)f2bf(v.y); t[6]=(short)f2bf(v.z); t[7]=(short)f2bf(v.w);
            afr[rt] = t;
        }
        #pragma unroll
        for (int rt = 0; rt < 4; ++rt)
            #pragma unroll
            for (int ct = 0; ct < 4; ++ct) {
                f32x4 z = {0.f, 0.f, 0.f, 0.f};
                acc[rt][ct] = mfma16(afr[rt], bfr[ct], z);
            }
        #pragma unroll
        for (int ct = 0; ct < 4; ++ct) {
            const float bb = b1[cb + ct * 16 + lr];
            #pragma unroll
            for (int rt = 0; rt < 4; ++rt)
                #pragma unroll
                for (int i = 0; i < 4; ++i) {
                    float h = fmaxf(acc[rt][ct][i] + bb, 0.f);
                    Hs[(rt * 16 + g * 4 + i) * 264 + cb + ct * 16 + lr] = f2bf(h);
                }
        }
    }
    __syncthreads();

    int wrow[4], hoff[4];
    #pragma unroll
    for (int ct = 0; ct < 4; ++ct) wrow[ct] = (cb + ct * 16 + lr) * 256 + g * 8;
    #pragma unroll
    for (int rt = 0; rt < 4; ++rt) hoff[rt] = (rt * 16 + lr) * 264 + g * 8;

    // ---- layer 2: K=256, 8 MFMA steps ----
    {
        f32x4 acc[4][4];
        #pragma unroll
        for (int rt = 0; rt < 4; ++rt)
            #pragma unroll
            for (int ct = 0; ct < 4; ++ct) acc[rt][ct] = (f32x4){0.f,0.f,0.f,0.f};

        #pragma unroll 2
        for (int kk = 0; kk < 8; ++kk) {
            bf16x8 bfr[4], afr[4];
            #pragma unroll
            for (int ct = 0; ct < 4; ++ct)
                bfr[ct] = *(const bf16x8*)&W2T[wrow[ct] + kk * 32];
            #pragma unroll
            for (int rt = 0; rt < 4; ++rt)
                afr[rt] = *(const bf16x8*)&Hs[hoff[rt] + kk * 32];
            #pragma unroll
            for (int rt = 0; rt < 4; ++rt)
                #pragma unroll
                for (int ct = 0; ct < 4; ++ct)
                    acc[rt][ct] = mfma16(afr[rt], bfr[ct], acc[rt][ct]);
        }
        __syncthreads();   // all Hs reads done before overwrite
        #pragma unroll
        for (int ct = 0; ct < 4; ++ct) {
            const float bb = b2[cb + ct * 16 + lr];
            #pragma unroll
            for (int rt = 0; rt < 4; ++rt)
                #pragma unroll
                for (int i = 0; i < 4; ++i) {
                    float h = fmaxf(acc[rt][ct][i] + bb, 0.f);
                    Hs[(rt * 16 + g * 4 + i) * 264 + cb + ct * 16 + lr] = f2bf(h);
                }
        }
    }
    __syncthreads();

    // ---- layer 3: K=256, 8 MFMA steps, fp32 out to y ----
    {
        f32x4 acc[4][4];
        #pragma unroll
        for (int rt = 0; rt < 4; ++rt)
            #pragma unroll
            for (int ct = 0; ct < 4; ++ct) acc[rt][ct] = (f32x4){0.f,0.f,0.f,0.f};

        #pragma unroll 2
        for (int kk = 0; kk < 8; ++kk) {
            bf16x8 bfr[4], afr[4];
            #pragma unroll
            for (int ct = 0; ct < 4; ++ct)
                bfr[ct] = *(const bf16x8*)&W3T[wrow[ct] + kk * 32];
            #pragma unroll
            for (int rt = 0; rt < 4; ++rt)
                afr[rt] = *(const bf16x8*)&Hs[hoff[rt] + kk * 32];
            #pragma unroll
            for (int rt = 0; rt < 4; ++rt)
                #pragma unroll
                for (int ct = 0; ct < 4; ++ct)
                    acc[rt][ct] = mfma16(afr[rt], bfr[ct], acc[rt][ct]);
        }
        #pragma unroll
        for (int ct = 0; ct < 4; ++ct) {
            const int c3 = cb + ct * 16 + lr;
            #pragma unroll
            for (int rt = 0; rt < 4; ++rt)
                #pragma unroll
                for (int i = 0; i < 4; ++i)
                    y[(row0 + rt * 16 + g * 4 + i) * OUTC + DIMX + c3] = acc[rt][ct][i];
        }
    }

    // xs -> y[.., 0:32]
    for (int i = tid; i < 512; i += 256) {
        int r = i >> 3, q = i & 7;
        *(float4*)&y[(row0 + r) * OUTC + q * 4] = *(const float4*)&Xf[r * 36 + q * 4];
    }
}

// ---------------------------------------------------------------------------
// K3: fp32 encoder for the 1024 t=0 rows ONLY (y0 feeds the scan; its error
// is amplified ~150x, so bf16 is not acceptable here). 8 rows/block.
// Overwrites y[n,0,32:288].
// ---------------------------------------------------------------------------
__global__ __launch_bounds__(256) void enc0_kernel(
    const float* __restrict__ xs,
    const float* __restrict__ W1, const float* __restrict__ b1,
    const float* __restrict__ W2, const float* __restrict__ b2,
    const float* __restrict__ W3,
    float* __restrict__ y)
{
    __shared__ float Xs[8 * 32];
    __shared__ float Hsf[8 * 256];
    const int tid = threadIdx.x;
    const int c   = tid;
    const int n0  = blockIdx.x * 8;

    if (tid < 64) {
        int r = tid >> 3, q = tid & 7;
        *(float4*)&Xs[r * 32 + q * 4] =
            *(const float4*)&xs[(size_t)(n0 + r) * (T_SEQ * DIMX) + q * 4];
    }
    __syncthreads();

    float acc[8];
    // L1
    {
        float w[32];
        #pragma unroll
        for (int d = 0; d < 32; ++d) w[d] = W1[d * ENCH + c];
        const float bb = b1[c];
        #pragma unroll
        for (int r = 0; r < 8; ++r) {
            float a = bb;
            #pragma unroll
            for (int d4 = 0; d4 < 8; ++d4) {
                float4 xv = *(const float4*)&Xs[r * 32 + d4 * 4];
                a += xv.x * w[d4*4] + xv.y * w[d4*4+1] + xv.z * w[d4*4+2] + xv.w * w[d4*4+3];
            }
            acc[r] = a;
        }
        #pragma unroll
        for (int r = 0; r < 8; ++r) Hsf[r * 256 + c] = fmaxf(acc[r], 0.f);
    }
    __syncthreads();
    // L2
    {
        const float bb = b2[c];
        #pragma unroll
        for (int r = 0; r < 8; ++r) acc[r] = bb;
        for (int hc = 0; hc < 8; ++hc) {
            float w[32];
            #pragma unroll
            for (int i = 0; i < 32; ++i) w[i] = W2[(hc * 32 + i) * ENCH + c];
            #pragma unroll
            for (int r = 0; r < 8; ++r) {
                float a = acc[r];
                #pragma unroll
                for (int h4 = 0; h4 < 8; ++h4) {
                    float4 hv = *(const float4*)&Hsf[r * 256 + hc * 32 + h4 * 4];
                    a += hv.x * w[h4*4] + hv.y * w[h4*4+1] + hv.z * w[h4*4+2] + hv.w * w[h4*4+3];
                }
                acc[r] = a;
            }
        }
        __syncthreads();
        #pragma unroll
        for (int r = 0; r < 8; ++r) Hsf[r * 256 + c] = fmaxf(acc[r], 0.f);
    }
    __syncthreads();
    // L3
    {
        #pragma unroll
        for (int r = 0; r < 8; ++r) acc[r] = 0.f;
        for (int hc = 0; hc < 8; ++hc) {
            float w[32];
            #pragma unroll
            for (int i = 0; i < 32; ++i) w[i] = W3[(hc * 32 + i) * LDIM + c];
            #pragma unroll
            for (int r = 0; r < 8; ++r) {
                float a = acc[r];
                #pragma unroll
                for (int h4 = 0; h4 < 8; ++h4) {
                    float4 hv = *(const float4*)&Hsf[r * 256 + hc * 32 + h4 * 4];
                    a += hv.x * w[h4*4] + hv.y * w[h4*4+1] + hv.z * w[h4*4+2] + hv.w * w[h4*4+3];
                }
                acc[r] = a;
            }
        }
    }
    #pragma unroll
    for (int r = 0; r < 8; ++r)
        y[((size_t)(n0 + r) * T_SEQ) * OUTC + DIMX + c] = acc[r];
}

// ---------------------------------------------------------------------------
// K4: closed-form scan + readout (ys[t] = z^t * y0, exact).
// ---------------------------------------------------------------------------
__global__ __launch_bounds__(256) void scan_kernel(
    const float* __restrict__ xs,
    const float* __restrict__ a_ws, const float* __restrict__ th_ws,
    const float* __restrict__ C_W,
    const float* __restrict__ y,
    float* __restrict__ yp)
{
    const int n   = blockIdx.x >> 3;
    const int tg  = blockIdx.x & 7;
    const int tid = threadIdx.x;
    const int k   = tid >> 1;

    __shared__ float ys_lds[8][256];

    const float* yrow0 = y + (size_t)n * T_SEQ * OUTC + DIMX;
    float2 y0 = *(const float2*)&yrow0[tid & ~1];
    const float a  = a_ws [n * NAUX + k];
    const float th = th_ws[n * NAUX + k];

    float* ypn = yp + (size_t)n * T_SEQ * OUTC;

    #pragma unroll
    for (int tt = 0; tt < 8; ++tt) {
        const int t = tg * 8 + tt;
        float val;
        if (t == 0) {
            val = (tid & 1) ? y0.y : y0.x;
        } else {
            const float tf = (float)t;
            const float m  = expf(a * tf);
            float ss, sc;
            sincosf(th * tf, &ss, &sc);
            const float v1 = m * (y0.x * sc - y0.y * ss);
            const float v2 = m * (y0.x * ss + y0.y * sc);
            val = (tid & 1) ? v2 : v1;
        }
        ypn[(size_t)t * OUTC + DIMX + tid] = val;
        ys_lds[tt][tid] = val;
    }
    __syncthreads();

    const int tt = tid >> 5, d = tid & 31;
    const int t  = tg * 8 + tt;
    float o;
    if (t == 0) {
        o = xs[(size_t)n * T_SEQ * DIMX + d];
    } else {
        float s = 0.f;
        #pragma unroll 8
        for (int l = 0; l < 256; l += 4) {
            float4 yv = *(const float4*)&ys_lds[tt][l];
            s += yv.x * C_W[(l    ) * DIMX + d]
               + yv.y * C_W[(l + 1) * DIMX + d]
               + yv.z * C_W[(l + 2) * DIMX + d]
               + yv.w * C_W[(l + 3) * DIMX + d];
        }
        o = s;
    }
    ypn[(size_t)t * OUTC + d] = o;
}

// ---------------------------------------------------------------------------
extern "C" void kernel_launch(void* const* d_in, const int* in_sizes, int n_in,
                              void* d_out, int out_size, void* d_ws, size_t ws_size,
                              hipStream_t stream)
{
    const float* xs   = (const float*)d_in[0];
    const float* eW1  = (const float*)d_in[1];
    const float* eb1  = (const float*)d_in[2];
    const float* eW2  = (const float*)d_in[3];
    const float* eb2  = (const float*)d_in[4];
    const float* eW3  = (const float*)d_in[5];
    const float* aW1  = (const float*)d_in[6];
    const float* ab1  = (const float*)d_in[7];
    const float* aW2  = (const float*)d_in[8];
    const float* ab2  = (const float*)d_in[9];
    const float* aW3  = (const float*)d_in[10];
    const float* C_W  = (const float*)d_in[11];

    float* y  = (float*)d_out;
    float* yp = y + (size_t)N_SEQ * T_SEQ * OUTC;

    float* a_ws  = (float*)d_ws;
    float* th_ws = a_ws + (size_t)N_SEQ * NAUX;
    unsigned short* wt = (unsigned short*)(th_ws + (size_t)N_SEQ * NAUX);
    unsigned short* W1T = wt;
    unsigned short* W2T = wt + 8192;
    unsigned short* W3T = wt + 8192 + 65536;

    convw_kernel<<<(8192 + 131072 + 255) / 256, 256, 0, stream>>>(eW1, eW2, eW3, wt);
    aux_kernel  <<<128 * 32, 256, 0, stream>>>(xs, aW1, ab1, aW2, ab2, aW3, a_ws, th_ws);
    encm_kernel <<<N_SEQ * T_SEQ / 64, 256, 0, stream>>>(xs, W1T, eb1, W2T, eb2, W3T, y);
    enc0_kernel <<<N_SEQ / 8, 256, 0, stream>>>(xs, eW1, eb1, eW2, eb2, eW3, y);
    scan_kernel <<<N_SEQ * 8, 256, 0, stream>>>(xs, a_ws, th_ws, C_W, y, yp);
}

// Round 3
// 217.567 us; speedup vs baseline: 3.1141x; 1.1266x over previous
//
#include <hip/hip_runtime.h>
#include <math.h>

#define N_SEQ 1024
#define T_SEQ 64
#define DIMX  32
#define LDIM  256
#define NAUX  128
#define AUXH  128
#define ENCH  256
#define OUTC  288           // DIMX + LDIM
#define DT    0.01f

typedef short bf16x8 __attribute__((ext_vector_type(8)));
typedef float f32x4  __attribute__((ext_vector_type(4)));

__device__ __forceinline__ unsigned short f2bf(float f) {
    unsigned u = __builtin_bit_cast(unsigned, f);
    unsigned r = u + 0x7fffu + ((u >> 16) & 1u);   // RNE
    return (unsigned short)(r >> 16);
}
__device__ __forceinline__ float bf2f(unsigned short h) {
    unsigned u = ((unsigned)h) << 16;
    return __builtin_bit_cast(float, u);
}
__device__ __forceinline__ f32x4 mfma16(bf16x8 a, bf16x8 b, f32x4 c) {
    return __builtin_amdgcn_mfma_f32_16x16x32_bf16(a, b, c, 0, 0, 0);
}

// ---------------------------------------------------------------------------
// K0: weight conversion.
//  - encoder W1/W2/W3 -> bf16 transposed [col][k]              (139264 ush)
//  - aux W1 -> hi/lo bf16 transposed per net: [k][j][d]        (524288 each)
//  - aux W2 -> hi/lo bf16 transposed per net: [k][j][h]        (2097152 each)
// ---------------------------------------------------------------------------
#define CV_ENC   139264
#define CV_A1    524288
#define CV_A2    2097152
__global__ __launch_bounds__(256) void convw_kernel(
    const float* __restrict__ eW1, const float* __restrict__ eW2,
    const float* __restrict__ eW3,
    const float* __restrict__ aW1, const float* __restrict__ aW2,
    unsigned short* __restrict__ encw,
    unsigned short* __restrict__ a1h, unsigned short* __restrict__ a1l,
    unsigned short* __restrict__ a2h, unsigned short* __restrict__ a2l)
{
    const int idx = blockIdx.x * 256 + threadIdx.x;
    if (idx < 8192) {                          // eW1T [256c][32k]
        int c = idx >> 5, k = idx & 31;
        encw[idx] = f2bf(eW1[k * ENCH + c]);
    } else if (idx < 8192 + 65536) {           // eW2T [256][256]
        int t = idx - 8192; int c = t >> 8, k = t & 255;
        encw[idx] = f2bf(eW2[k * ENCH + c]);
    } else if (idx < CV_ENC) {                 // eW3T [256][256]
        int t = idx - (8192 + 65536); int c = t >> 8, k = t & 255;
        encw[idx] = f2bf(eW3[k * LDIM + c]);
    } else if (idx < CV_ENC + CV_A1) {         // aux W1T hi/lo
        int t = idx - CV_ENC;
        int k = t >> 12, r = t & 4095, j = r >> 5, d = r & 31;
        float w = aW1[(size_t)k * 4096 + d * 128 + j];
        unsigned short hi = f2bf(w);
        a1h[t] = hi;
        a1l[t] = f2bf(w - bf2f(hi));
    } else if (idx < CV_ENC + CV_A1 + CV_A2) { // aux W2T hi/lo
        int t = idx - (CV_ENC + CV_A1);
        int k = t >> 14, r = t & 16383, j = r >> 7, h = r & 127;
        float w = aW2[(size_t)k * 16384 + h * 128 + j];
        unsigned short hi = f2bf(w);
        a2h[t] = hi;
        a2l[t] = f2bf(w - bf2f(hi));
    }
}

// ---------------------------------------------------------------------------
// K1: aux MLPs via split-bf16 MFMA (3-product: hi*hi + lo*hi + hi*lo,
// residual ~2^-18 — safe under the ~300x scan amplification).
// Block = (aux net k, 64 n's). 4 waves; wave wv owns cols wv*32..+31.
// ---------------------------------------------------------------------------
__global__ __launch_bounds__(256) void auxm_kernel(
    const float* __restrict__ xs,
    const unsigned short* __restrict__ W1h, const unsigned short* __restrict__ W1l,
    const float* __restrict__ b1,
    const unsigned short* __restrict__ W2h, const unsigned short* __restrict__ W2l,
    const float* __restrict__ b2,
    const float* __restrict__ W3,
    float* __restrict__ a_ws, float* __restrict__ th_ws)
{
    const int k   = blockIdx.x >> 4;          // aux net (128)
    const int n0  = (blockIdx.x & 15) << 6;   // 64 n's
    const int tid = threadIdx.x;
    const int wv  = tid >> 6;
    const int ln  = tid & 63;
    const int lr  = ln & 15;
    const int g   = ln >> 4;
    const int cb  = wv * 32;                  // col block (2x16 tiles)

    __shared__ float          x0s[64][36];
    __shared__ unsigned short h1h[64][136];
    __shared__ unsigned short h1l[64][136];
    __shared__ float          h2f[64][132];

    // stage x0 rows (n0..n0+63)
    {
        for (int i = tid; i < 512; i += 256) {
            int r = i >> 3, q = i & 7;
            *(float4*)&x0s[r][q * 4] =
                *(const float4*)&xs[(size_t)(n0 + r) * (T_SEQ * DIMX) + q * 4];
        }
    }
    __syncthreads();

    // ---- layer 1: M=64, N=128(32/wave), K=32 ----
    {
        const unsigned short* W1hk = W1h + (size_t)k * 4096;
        const unsigned short* W1lk = W1l + (size_t)k * 4096;
        bf16x8 bh[2], bl[2];
        #pragma unroll
        for (int ct = 0; ct < 2; ++ct) {
            int off = (cb + ct * 16 + lr) * 32 + g * 8;
            bh[ct] = *(const bf16x8*)&W1hk[off];
            bl[ct] = *(const bf16x8*)&W1lk[off];
        }
        f32x4 acc[4][2];
        #pragma unroll
        for (int rt = 0; rt < 4; ++rt) {
            const float* xp = &x0s[rt * 16 + lr][g * 8];
            bf16x8 ah, al;
            #pragma unroll
            for (int e = 0; e < 8; ++e) {
                float x = xp[e];
                unsigned short hi = f2bf(x);
                ah[e] = (short)hi;
                al[e] = (short)f2bf(x - bf2f(hi));
            }
            #pragma unroll
            for (int ct = 0; ct < 2; ++ct) {
                f32x4 z = {0.f, 0.f, 0.f, 0.f};
                z = mfma16(ah, bl[ct], z);
                z = mfma16(al, bh[ct], z);
                acc[rt][ct] = mfma16(ah, bh[ct], z);
            }
        }
        #pragma unroll
        for (int ct = 0; ct < 2; ++ct) {
            const int col = cb + ct * 16 + lr;
            const float bb = b1[k * 128 + col];
            #pragma unroll
            for (int rt = 0; rt < 4; ++rt)
                #pragma unroll
                for (int i = 0; i < 4; ++i) {
                    float h = fmaxf(acc[rt][ct][i] + bb, 0.f);
                    unsigned short hi = f2bf(h);
                    int row = rt * 16 + g * 4 + i;
                    h1h[row][col] = hi;
                    h1l[row][col] = f2bf(h - bf2f(hi));
                }
        }
    }
    __syncthreads();

    // ---- layer 2: M=64, N=128(32/wave), K=128 (4 steps) ----
    {
        const unsigned short* W2hk = W2h + (size_t)k * 16384;
        const unsigned short* W2lk = W2l + (size_t)k * 16384;
        f32x4 acc[4][2];
        #pragma unroll
        for (int rt = 0; rt < 4; ++rt)
            #pragma unroll
            for (int ct = 0; ct < 2; ++ct) acc[rt][ct] = (f32x4){0.f,0.f,0.f,0.f};

        #pragma unroll
        for (int kk = 0; kk < 4; ++kk) {
            bf16x8 bh[2], bl[2], ah[4], al[4];
            #pragma unroll
            for (int ct = 0; ct < 2; ++ct) {
                int off = (cb + ct * 16 + lr) * 128 + kk * 32 + g * 8;
                bh[ct] = *(const bf16x8*)&W2hk[off];
                bl[ct] = *(const bf16x8*)&W2lk[off];
            }
            #pragma unroll
            for (int rt = 0; rt < 4; ++rt) {
                ah[rt] = *(const bf16x8*)&h1h[rt * 16 + lr][kk * 32 + g * 8];
                al[rt] = *(const bf16x8*)&h1l[rt * 16 + lr][kk * 32 + g * 8];
            }
            #pragma unroll
            for (int rt = 0; rt < 4; ++rt)
                #pragma unroll
                for (int ct = 0; ct < 2; ++ct) {
                    f32x4 z = acc[rt][ct];
                    z = mfma16(ah[rt], bl[ct], z);
                    z = mfma16(al[rt], bh[ct], z);
                    acc[rt][ct] = mfma16(ah[rt], bh[ct], z);
                }
        }
        #pragma unroll
        for (int ct = 0; ct < 2; ++ct) {
            const int col = cb + ct * 16 + lr;
            const float bb = b2[k * 128 + col];
            #pragma unroll
            for (int rt = 0; rt < 4; ++rt)
                #pragma unroll
                for (int i = 0; i < 4; ++i)
                    h2f[rt * 16 + g * 4 + i][col] = fmaxf(acc[rt][ct][i] + bb, 0.f);
        }
    }
    __syncthreads();

    // ---- layer 3: aux[n][o] = sum_h h2[n][h]*W3k[h][o], fp32 ----
    if (tid < 128) {
        const int n = tid >> 1, o = tid & 1;
        const float* W3k = W3 + (size_t)k * (AUXH * 2);
        float s = 0.f;
        #pragma unroll 4
        for (int h = 0; h < 128; ++h)
            s += h2f[n][h] * W3k[h * 2 + o];
        float* dst = o ? th_ws : a_ws;
        dst[(size_t)(n0 + n) * NAUX + k] = s * DT;
    }
}

// ---------------------------------------------------------------------------
// K2: encoder via bf16 MFMA (unchanged from R2 — validated).
// ---------------------------------------------------------------------------
__global__ __launch_bounds__(256) void encm_kernel(
    const float* __restrict__ xs,
    const unsigned short* __restrict__ W1T, const float* __restrict__ b1,
    const unsigned short* __restrict__ W2T, const float* __restrict__ b2,
    const unsigned short* __restrict__ W3T,
    float* __restrict__ y)
{
    __shared__ float          Xf[64 * 36];
    __shared__ unsigned short Hs[64 * 264];

    const int tid = threadIdx.x;
    const int wv  = tid >> 6;
    const int ln  = tid & 63;
    const int lr  = ln & 15;
    const int g   = ln >> 4;
    const int cb  = wv * 64;
    const size_t row0 = (size_t)blockIdx.x * 64;

    {
        const float4* src = (const float4*)(xs + row0 * DIMX);
        for (int i = tid; i < 512; i += 256) {
            int r = i >> 3, q = i & 7;
            *(float4*)&Xf[r * 36 + q * 4] = src[i];
        }
    }
    __syncthreads();

    // layer 1 (K=32)
    {
        f32x4 acc[4][4];
        bf16x8 bfr[4], afr[4];
        #pragma unroll
        for (int ct = 0; ct < 4; ++ct)
            bfr[ct] = *(const bf16x8*)&W1T[(cb + ct * 16 + lr) * 32 + g * 8];
        #pragma unroll
        for (int rt = 0; rt < 4; ++rt) {
            const float* xp = &Xf[(rt * 16 + lr) * 36 + g * 8];
            float4 u = *(const float4*)xp;
            float4 v = *(const float4*)(xp + 4);
            bf16x8 t;
            t[0]=(short)f2bf(u.x); t[1]=(short)f2bf(u.y); t[2]=(short)f2bf(u.z); t[3]=(short)f2bf(u.w);
            t[4]=(short)f2bf(v.x); t[5]=(short)f2bf(v.y); t[6]=(short)f2bf(v.z); t[7]=(short)f2bf(v.w);
            afr[rt] = t;
        }
        #pragma unroll
        for (int rt = 0; rt < 4; ++rt)
            #pragma unroll
            for (int ct = 0; ct < 4; ++ct) {
                f32x4 z = {0.f, 0.f, 0.f, 0.f};
                acc[rt][ct] = mfma16(afr[rt], bfr[ct], z);
            }
        #pragma unroll
        for (int ct = 0; ct < 4; ++ct) {
            const float bb = b1[cb + ct * 16 + lr];
            #pragma unroll
            for (int rt = 0; rt < 4; ++rt)
                #pragma unroll
                for (int i = 0; i < 4; ++i) {
                    float h = fmaxf(acc[rt][ct][i] + bb, 0.f);
                    Hs[(rt * 16 + g * 4 + i) * 264 + cb + ct * 16 + lr] = f2bf(h);
                }
        }
    }
    __syncthreads();

    int wrow[4], hoff[4];
    #pragma unroll
    for (int ct = 0; ct < 4; ++ct) wrow[ct] = (cb + ct * 16 + lr) * 256 + g * 8;
    #pragma unroll
    for (int rt = 0; rt < 4; ++rt) hoff[rt] = (rt * 16 + lr) * 264 + g * 8;

    // layer 2 (K=256)
    {
        f32x4 acc[4][4];
        #pragma unroll
        for (int rt = 0; rt < 4; ++rt)
            #pragma unroll
            for (int ct = 0; ct < 4; ++ct) acc[rt][ct] = (f32x4){0.f,0.f,0.f,0.f};
        #pragma unroll 2
        for (int kk = 0; kk < 8; ++kk) {
            bf16x8 bfr[4], afr[4];
            #pragma unroll
            for (int ct = 0; ct < 4; ++ct)
                bfr[ct] = *(const bf16x8*)&W2T[wrow[ct] + kk * 32];
            #pragma unroll
            for (int rt = 0; rt < 4; ++rt)
                afr[rt] = *(const bf16x8*)&Hs[hoff[rt] + kk * 32];
            #pragma unroll
            for (int rt = 0; rt < 4; ++rt)
                #pragma unroll
                for (int ct = 0; ct < 4; ++ct)
                    acc[rt][ct] = mfma16(afr[rt], bfr[ct], acc[rt][ct]);
        }
        __syncthreads();
        #pragma unroll
        for (int ct = 0; ct < 4; ++ct) {
            const float bb = b2[cb + ct * 16 + lr];
            #pragma unroll
            for (int rt = 0; rt < 4; ++rt)
                #pragma unroll
                for (int i = 0; i < 4; ++i) {
                    float h = fmaxf(acc[rt][ct][i] + bb, 0.f);
                    Hs[(rt * 16 + g * 4 + i) * 264 + cb + ct * 16 + lr] = f2bf(h);
                }
        }
    }
    __syncthreads();

    // layer 3 (K=256)
    {
        f32x4 acc[4][4];
        #pragma unroll
        for (int rt = 0; rt < 4; ++rt)
            #pragma unroll
            for (int ct = 0; ct < 4; ++ct) acc[rt][ct] = (f32x4){0.f,0.f,0.f,0.f};
        #pragma unroll 2
        for (int kk = 0; kk < 8; ++kk) {
            bf16x8 bfr[4], afr[4];
            #pragma unroll
            for (int ct = 0; ct < 4; ++ct)
                bfr[ct] = *(const bf16x8*)&W3T[wrow[ct] + kk * 32];
            #pragma unroll
            for (int rt = 0; rt < 4; ++rt)
                afr[rt] = *(const bf16x8*)&Hs[hoff[rt] + kk * 32];
            #pragma unroll
            for (int rt = 0; rt < 4; ++rt)
                #pragma unroll
                for (int ct = 0; ct < 4; ++ct)
                    acc[rt][ct] = mfma16(afr[rt], bfr[ct], acc[rt][ct]);
        }
        #pragma unroll
        for (int ct = 0; ct < 4; ++ct) {
            const int c3 = cb + ct * 16 + lr;
            #pragma unroll
            for (int rt = 0; rt < 4; ++rt)
                #pragma unroll
                for (int i = 0; i < 4; ++i)
                    y[(row0 + rt * 16 + g * 4 + i) * OUTC + DIMX + c3] = acc[rt][ct][i];
        }
    }

    for (int i = tid; i < 512; i += 256) {
        int r = i >> 3, q = i & 7;
        *(float4*)&y[(row0 + r) * OUTC + q * 4] = *(const float4*)&Xf[r * 36 + q * 4];
    }
}

// ---------------------------------------------------------------------------
// K3: fp32 encoder for the 1024 t=0 rows (y0 precision). Unchanged.
// ---------------------------------------------------------------------------
__global__ __launch_bounds__(256) void enc0_kernel(
    const float* __restrict__ xs,
    const float* __restrict__ W1, const float* __restrict__ b1,
    const float* __restrict__ W2, const float* __restrict__ b2,
    const float* __restrict__ W3,
    float* __restrict__ y)
{
    __shared__ float Xs[8 * 32];
    __shared__ float Hsf[8 * 256];
    const int tid = threadIdx.x;
    const int c   = tid;
    const int n0  = blockIdx.x * 8;

    if (tid < 64) {
        int r = tid >> 3, q = tid & 7;
        *(float4*)&Xs[r * 32 + q * 4] =
            *(const float4*)&xs[(size_t)(n0 + r) * (T_SEQ * DIMX) + q * 4];
    }
    __syncthreads();

    float acc[8];
    {
        float w[32];
        #pragma unroll
        for (int d = 0; d < 32; ++d) w[d] = W1[d * ENCH + c];
        const float bb = b1[c];
        #pragma unroll
        for (int r = 0; r < 8; ++r) {
            float a = bb;
            #pragma unroll
            for (int d4 = 0; d4 < 8; ++d4) {
                float4 xv = *(const float4*)&Xs[r * 32 + d4 * 4];
                a += xv.x * w[d4*4] + xv.y * w[d4*4+1] + xv.z * w[d4*4+2] + xv.w * w[d4*4+3];
            }
            acc[r] = a;
        }
        #pragma unroll
        for (int r = 0; r < 8; ++r) Hsf[r * 256 + c] = fmaxf(acc[r], 0.f);
    }
    __syncthreads();
    {
        const float bb = b2[c];
        #pragma unroll
        for (int r = 0; r < 8; ++r) acc[r] = bb;
        for (int hc = 0; hc < 8; ++hc) {
            float w[32];
            #pragma unroll
            for (int i = 0; i < 32; ++i) w[i] = W2[(hc * 32 + i) * ENCH + c];
            #pragma unroll
            for (int r = 0; r < 8; ++r) {
                float a = acc[r];
                #pragma unroll
                for (int h4 = 0; h4 < 8; ++h4) {
                    float4 hv = *(const float4*)&Hsf[r * 256 + hc * 32 + h4 * 4];
                    a += hv.x * w[h4*4] + hv.y * w[h4*4+1] + hv.z * w[h4*4+2] + hv.w * w[h4*4+3];
                }
                acc[r] = a;
            }
        }
        __syncthreads();
        #pragma unroll
        for (int r = 0; r < 8; ++r) Hsf[r * 256 + c] = fmaxf(acc[r], 0.f);
    }
    __syncthreads();
    {
        #pragma unroll
        for (int r = 0; r < 8; ++r) acc[r] = 0.f;
        for (int hc = 0; hc < 8; ++hc) {
            float w[32];
            #pragma unroll
            for (int i = 0; i < 32; ++i) w[i] = W3[(hc * 32 + i) * LDIM + c];
            #pragma unroll
            for (int r = 0; r < 8; ++r) {
                float a = acc[r];
                #pragma unroll
                for (int h4 = 0; h4 < 8; ++h4) {
                    float4 hv = *(const float4*)&Hsf[r * 256 + hc * 32 + h4 * 4];
                    a += hv.x * w[h4*4] + hv.y * w[h4*4+1] + hv.z * w[h4*4+2] + hv.w * w[h4*4+3];
                }
                acc[r] = a;
            }
        }
    }
    #pragma unroll
    for (int r = 0; r < 8; ++r)
        y[((size_t)(n0 + r) * T_SEQ) * OUTC + DIMX + c] = acc[r];
}

// ---------------------------------------------------------------------------
// K4: closed-form scan + readout (ys[t] = z^t * y0). Unchanged.
// ---------------------------------------------------------------------------
__global__ __launch_bounds__(256) void scan_kernel(
    const float* __restrict__ xs,
    const float* __restrict__ a_ws, const float* __restrict__ th_ws,
    const float* __restrict__ C_W,
    const float* __restrict__ y,
    float* __restrict__ yp)
{
    const int n   = blockIdx.x >> 3;
    const int tg  = blockIdx.x & 7;
    const int tid = threadIdx.x;
    const int k   = tid >> 1;

    __shared__ float ys_lds[8][256];

    const float* yrow0 = y + (size_t)n * T_SEQ * OUTC + DIMX;
    float2 y0 = *(const float2*)&yrow0[tid & ~1];
    const float a  = a_ws [n * NAUX + k];
    const float th = th_ws[n * NAUX + k];

    float* ypn = yp + (size_t)n * T_SEQ * OUTC;

    #pragma unroll
    for (int tt = 0; tt < 8; ++tt) {
        const int t = tg * 8 + tt;
        float val;
        if (t == 0) {
            val = (tid & 1) ? y0.y : y0.x;
        } else {
            const float tf = (float)t;
            const float m  = expf(a * tf);
            float ss, sc;
            sincosf(th * tf, &ss, &sc);
            const float v1 = m * (y0.x * sc - y0.y * ss);
            const float v2 = m * (y0.x * ss + y0.y * sc);
            val = (tid & 1) ? v2 : v1;
        }
        ypn[(size_t)t * OUTC + DIMX + tid] = val;
        ys_lds[tt][tid] = val;
    }
    __syncthreads();

    const int tt = tid >> 5, d = tid & 31;
    const int t  = tg * 8 + tt;
    float o;
    if (t == 0) {
        o = xs[(size_t)n * T_SEQ * DIMX + d];
    } else {
        float s = 0.f;
        #pragma unroll 8
        for (int l = 0; l < 256; l += 4) {
            float4 yv = *(const float4*)&ys_lds[tt][l];
            s += yv.x * C_W[(l    ) * DIMX + d]
               + yv.y * C_W[(l + 1) * DIMX + d]
               + yv.z * C_W[(l + 2) * DIMX + d]
               + yv.w * C_W[(l + 3) * DIMX + d];
        }
        o = s;
    }
    ypn[(size_t)t * OUTC + d] = o;
}

// ---------------------------------------------------------------------------
extern "C" void kernel_launch(void* const* d_in, const int* in_sizes, int n_in,
                              void* d_out, int out_size, void* d_ws, size_t ws_size,
                              hipStream_t stream)
{
    const float* xs   = (const float*)d_in[0];
    const float* eW1  = (const float*)d_in[1];
    const float* eb1  = (const float*)d_in[2];
    const float* eW2  = (const float*)d_in[3];
    const float* eb2  = (const float*)d_in[4];
    const float* eW3  = (const float*)d_in[5];
    const float* aW1  = (const float*)d_in[6];
    const float* ab1  = (const float*)d_in[7];
    const float* aW2  = (const float*)d_in[8];
    const float* ab2  = (const float*)d_in[9];
    const float* aW3  = (const float*)d_in[10];
    const float* C_W  = (const float*)d_in[11];

    float* y  = (float*)d_out;
    float* yp = y + (size_t)N_SEQ * T_SEQ * OUTC;

    // workspace layout
    float* a_ws  = (float*)d_ws;                         // 512K floats
    float* th_ws = a_ws + (size_t)N_SEQ * NAUX;          // 512K floats
    unsigned short* encw = (unsigned short*)(th_ws + (size_t)N_SEQ * NAUX);
    unsigned short* W1T = encw;
    unsigned short* W2T = encw + 8192;
    unsigned short* W3T = encw + 8192 + 65536;
    unsigned short* a1h = encw + CV_ENC;
    unsigned short* a1l = a1h + CV_A1;
    unsigned short* a2h = a1l + CV_A1;
    unsigned short* a2l = a2h + CV_A2;

    const int cv_total = CV_ENC + CV_A1 + CV_A2;
    convw_kernel<<<(cv_total + 255) / 256, 256, 0, stream>>>(
        eW1, eW2, eW3, aW1, aW2, encw, a1h, a1l, a2h, a2l);
    auxm_kernel <<<128 * 16, 256, 0, stream>>>(
        xs, a1h, a1l, ab1, a2h, a2l, ab2, aW3, a_ws, th_ws);
    encm_kernel <<<N_SEQ * T_SEQ / 64, 256, 0, stream>>>(xs, W1T, eb1, W2T, eb2, W3T, y);
    enc0_kernel <<<N_SEQ / 8, 256, 0, stream>>>(xs, eW1, eb1, eW2, eb2, eW3, y);
    scan_kernel <<<N_SEQ * 8, 256, 0, stream>>>(xs, a_ws, th_ws, C_W, y, yp);
}

// Round 4
// 210.143 us; speedup vs baseline: 3.2242x; 1.0353x over previous
//
#include <hip/hip_runtime.h>
#include <math.h>

#define N_SEQ 1024
#define T_SEQ 64
#define DIMX  32
#define LDIM  256
#define NAUX  128
#define AUXH  128
#define ENCH  256
#define OUTC  288           // DIMX + LDIM
#define DT    0.01f

typedef short bf16x8 __attribute__((ext_vector_type(8)));
typedef float f32x4  __attribute__((ext_vector_type(4)));

__device__ __forceinline__ unsigned short f2bf(float f) {
    unsigned u = __builtin_bit_cast(unsigned, f);
    unsigned r = u + 0x7fffu + ((u >> 16) & 1u);   // RNE
    return (unsigned short)(r >> 16);
}
__device__ __forceinline__ float bf2f(unsigned short h) {
    unsigned u = ((unsigned)h) << 16;
    return __builtin_bit_cast(float, u);
}
__device__ __forceinline__ f32x4 mfma16(bf16x8 a, bf16x8 b, f32x4 c) {
    return __builtin_amdgcn_mfma_f32_16x16x32_bf16(a, b, c, 0, 0, 0);
}

// ---------------------------------------------------------------------------
// K0a: encoder weights -> bf16 transposed [col][k]; C_W -> fp32 transposed.
// ---------------------------------------------------------------------------
#define CV_ENC   139264                         // 8192 + 65536 + 65536
__global__ __launch_bounds__(256) void convw_kernel(
    const float* __restrict__ eW1, const float* __restrict__ eW2,
    const float* __restrict__ eW3, const float* __restrict__ C_W,
    unsigned short* __restrict__ encw, float* __restrict__ cwt)
{
    const int idx = blockIdx.x * 256 + threadIdx.x;
    if (idx < 8192) {                          // eW1T [256c][32k]
        int c = idx >> 5, k = idx & 31;
        encw[idx] = f2bf(eW1[k * ENCH + c]);
    } else if (idx < 8192 + 65536) {           // eW2T [256][256]
        int t = idx - 8192; int c = t >> 8, k = t & 255;
        encw[idx] = f2bf(eW2[k * ENCH + c]);
    } else if (idx < CV_ENC) {                 // eW3T [256][256]
        int t = idx - (8192 + 65536); int c = t >> 8, k = t & 255;
        encw[idx] = f2bf(eW3[k * LDIM + c]);
    } else if (idx < CV_ENC + 8192) {          // C_WT [32d][256l] fp32
        int t = idx - CV_ENC; int d = t >> 8, l = t & 255;
        cwt[t] = C_W[l * DIMX + d];
    }
}

// ---------------------------------------------------------------------------
// K0b: aux W1/W2 -> hi/lo bf16 transposed per net, via 32x32 LDS tiles
// (both global directions coalesced).
//  aW1 [k][32d][128j] -> [k][j][32d]   : 512 tile jobs
//  aW2 [k][128h][128j] -> [k][j][128h] : 2048 tile jobs
// ---------------------------------------------------------------------------
__global__ __launch_bounds__(256) void transw_kernel(
    const float* __restrict__ aW1, const float* __restrict__ aW2,
    unsigned short* __restrict__ a1h, unsigned short* __restrict__ a1l,
    unsigned short* __restrict__ a2h, unsigned short* __restrict__ a2l)
{
    __shared__ float tile[32][33];
    const int b   = blockIdx.x;
    const int tid = threadIdx.x;

    const float* src; unsigned short *dh, *dl; int R, j0, r0;
    if (b < 512) {
        int k = b >> 2; j0 = (b & 3) * 32; r0 = 0; R = 32;
        src = aW1 + (size_t)k * 4096;
        dh = a1h + (size_t)k * 4096; dl = a1l + (size_t)k * 4096;
    } else {
        int bb = b - 512;
        int k = bb >> 4; j0 = ((bb >> 2) & 3) * 32; r0 = (bb & 3) * 32; R = 128;
        src = aW2 + (size_t)k * 16384;
        dh = a2h + (size_t)k * 16384; dl = a2l + (size_t)k * 16384;
    }

    for (int i = tid; i < 1024; i += 256) {
        int rr = i >> 5, jj = i & 31;
        tile[rr][jj] = src[(r0 + rr) * 128 + j0 + jj];
    }
    __syncthreads();
    for (int i = tid; i < 1024; i += 256) {
        int jj = i >> 5, rr = i & 31;
        float w = tile[rr][jj];
        unsigned short hi = f2bf(w);
        int off = (j0 + jj) * R + r0 + rr;
        dh[off] = hi;
        dl[off] = f2bf(w - bf2f(hi));
    }
}

// ---------------------------------------------------------------------------
// K1: aux MLPs via split-bf16 MFMA (3-product hi*hi + lo*hi + hi*lo).
// Block = (aux net k, 64 n's). 4 waves; wave wv owns cols wv*32..+31.
// ---------------------------------------------------------------------------
__global__ __launch_bounds__(256) void auxm_kernel(
    const float* __restrict__ xs,
    const unsigned short* __restrict__ W1h, const unsigned short* __restrict__ W1l,
    const float* __restrict__ b1,
    const unsigned short* __restrict__ W2h, const unsigned short* __restrict__ W2l,
    const float* __restrict__ b2,
    const float* __restrict__ W3,
    float* __restrict__ a_ws, float* __restrict__ th_ws)
{
    const int k   = blockIdx.x >> 4;
    const int n0  = (blockIdx.x & 15) << 6;
    const int tid = threadIdx.x;
    const int wv  = tid >> 6;
    const int ln  = tid & 63;
    const int lr  = ln & 15;
    const int g   = ln >> 4;
    const int cb  = wv * 32;

    __shared__ float          x0s[64][36];
    __shared__ unsigned short h1h[64][136];
    __shared__ unsigned short h1l[64][136];
    __shared__ float          h2f[64][133];
    __shared__ float          p3[256];

    for (int i = tid; i < 512; i += 256) {
        int r = i >> 3, q = i & 7;
        *(float4*)&x0s[r][q * 4] =
            *(const float4*)&xs[(size_t)(n0 + r) * (T_SEQ * DIMX) + q * 4];
    }
    __syncthreads();

    // ---- layer 1: M=64, N=128(32/wave), K=32 ----
    {
        const unsigned short* W1hk = W1h + (size_t)k * 4096;
        const unsigned short* W1lk = W1l + (size_t)k * 4096;
        bf16x8 bh[2], bl[2];
        #pragma unroll
        for (int ct = 0; ct < 2; ++ct) {
            int off = (cb + ct * 16 + lr) * 32 + g * 8;
            bh[ct] = *(const bf16x8*)&W1hk[off];
            bl[ct] = *(const bf16x8*)&W1lk[off];
        }
        f32x4 acc[4][2];
        #pragma unroll
        for (int rt = 0; rt < 4; ++rt) {
            const float* xp = &x0s[rt * 16 + lr][g * 8];
            bf16x8 ah, al;
            #pragma unroll
            for (int e = 0; e < 8; ++e) {
                float x = xp[e];
                unsigned short hi = f2bf(x);
                ah[e] = (short)hi;
                al[e] = (short)f2bf(x - bf2f(hi));
            }
            #pragma unroll
            for (int ct = 0; ct < 2; ++ct) {
                f32x4 z = {0.f, 0.f, 0.f, 0.f};
                z = mfma16(ah, bl[ct], z);
                z = mfma16(al, bh[ct], z);
                acc[rt][ct] = mfma16(ah, bh[ct], z);
            }
        }
        #pragma unroll
        for (int ct = 0; ct < 2; ++ct) {
            const int col = cb + ct * 16 + lr;
            const float bb = b1[k * 128 + col];
            #pragma unroll
            for (int rt = 0; rt < 4; ++rt)
                #pragma unroll
                for (int i = 0; i < 4; ++i) {
                    float h = fmaxf(acc[rt][ct][i] + bb, 0.f);
                    unsigned short hi = f2bf(h);
                    int row = rt * 16 + g * 4 + i;
                    h1h[row][col] = hi;
                    h1l[row][col] = f2bf(h - bf2f(hi));
                }
        }
    }
    __syncthreads();

    // ---- layer 2: M=64, N=128(32/wave), K=128 (4 steps) ----
    {
        const unsigned short* W2hk = W2h + (size_t)k * 16384;
        const unsigned short* W2lk = W2l + (size_t)k * 16384;
        f32x4 acc[4][2];
        #pragma unroll
        for (int rt = 0; rt < 4; ++rt)
            #pragma unroll
            for (int ct = 0; ct < 2; ++ct) acc[rt][ct] = (f32x4){0.f,0.f,0.f,0.f};

        #pragma unroll
        for (int kk = 0; kk < 4; ++kk) {
            bf16x8 bh[2], bl[2], ah[4], al[4];
            #pragma unroll
            for (int ct = 0; ct < 2; ++ct) {
                int off = (cb + ct * 16 + lr) * 128 + kk * 32 + g * 8;
                bh[ct] = *(const bf16x8*)&W2hk[off];
                bl[ct] = *(const bf16x8*)&W2lk[off];
            }
            #pragma unroll
            for (int rt = 0; rt < 4; ++rt) {
                ah[rt] = *(const bf16x8*)&h1h[rt * 16 + lr][kk * 32 + g * 8];
                al[rt] = *(const bf16x8*)&h1l[rt * 16 + lr][kk * 32 + g * 8];
            }
            #pragma unroll
            for (int rt = 0; rt < 4; ++rt)
                #pragma unroll
                for (int ct = 0; ct < 2; ++ct) {
                    f32x4 z = acc[rt][ct];
                    z = mfma16(ah[rt], bl[ct], z);
                    z = mfma16(al[rt], bh[ct], z);
                    acc[rt][ct] = mfma16(ah[rt], bh[ct], z);
                }
        }
        #pragma unroll
        for (int ct = 0; ct < 2; ++ct) {
            const int col = cb + ct * 16 + lr;
            const float bb = b2[k * 128 + col];
            #pragma unroll
            for (int rt = 0; rt < 4; ++rt)
                #pragma unroll
                for (int i = 0; i < 4; ++i)
                    h2f[rt * 16 + g * 4 + i][col] = fmaxf(acc[rt][ct][i] + bb, 0.f);
        }
    }
    __syncthreads();

    // ---- layer 3: all 256 threads (h halves), LDS combine ----
    {
        const int hh = tid >> 7, r = tid & 127, n = r >> 1, o = r & 1;
        const float* W3k = W3 + (size_t)k * (AUXH * 2);
        float s = 0.f;
        #pragma unroll 8
        for (int h = hh * 64; h < hh * 64 + 64; ++h)
            s += h2f[n][h] * W3k[h * 2 + o];
        p3[tid] = s;
    }
    __syncthreads();
    if (tid < 128) {
        const int n = tid >> 1, o = tid & 1;
        float v = (p3[tid] + p3[tid + 128]) * DT;
        float* dst = o ? th_ws : a_ws;
        dst[(size_t)(n0 + n) * NAUX + k] = v;
    }
}

// ---------------------------------------------------------------------------
// K2: encoder via bf16 MFMA (validated).
// ---------------------------------------------------------------------------
__global__ __launch_bounds__(256) void encm_kernel(
    const float* __restrict__ xs,
    const unsigned short* __restrict__ W1T, const float* __restrict__ b1,
    const unsigned short* __restrict__ W2T, const float* __restrict__ b2,
    const unsigned short* __restrict__ W3T,
    float* __restrict__ y)
{
    __shared__ float          Xf[64 * 36];
    __shared__ unsigned short Hs[64 * 264];

    const int tid = threadIdx.x;
    const int wv  = tid >> 6;
    const int ln  = tid & 63;
    const int lr  = ln & 15;
    const int g   = ln >> 4;
    const int cb  = wv * 64;
    const size_t row0 = (size_t)blockIdx.x * 64;

    {
        const float4* src = (const float4*)(xs + row0 * DIMX);
        for (int i = tid; i < 512; i += 256) {
            int r = i >> 3, q = i & 7;
            *(float4*)&Xf[r * 36 + q * 4] = src[i];
        }
    }
    __syncthreads();

    // layer 1 (K=32)
    {
        f32x4 acc[4][4];
        bf16x8 bfr[4], afr[4];
        #pragma unroll
        for (int ct = 0; ct < 4; ++ct)
            bfr[ct] = *(const bf16x8*)&W1T[(cb + ct * 16 + lr) * 32 + g * 8];
        #pragma unroll
        for (int rt = 0; rt < 4; ++rt) {
            const float* xp = &Xf[(rt * 16 + lr) * 36 + g * 8];
            float4 u = *(const float4*)xp;
            float4 v = *(const float4*)(xp + 4);
            bf16x8 t;
            t[0]=(short)f2bf(u.x); t[1]=(short)f2bf(u.y); t[2]=(short)f2bf(u.z); t[3]=(short)f2bf(u.w);
            t[4]=(short)f2bf(v.x); t[5]=(short)f2bf(v.y); t[6]=(short)f2bf(v.z); t[7]=(short)f2bf(v.w);
            afr[rt] = t;
        }
        #pragma unroll
        for (int rt = 0; rt < 4; ++rt)
            #pragma unroll
            for (int ct = 0; ct < 4; ++ct) {
                f32x4 z = {0.f, 0.f, 0.f, 0.f};
                acc[rt][ct] = mfma16(afr[rt], bfr[ct], z);
            }
        #pragma unroll
        for (int ct = 0; ct < 4; ++ct) {
            const float bb = b1[cb + ct * 16 + lr];
            #pragma unroll
            for (int rt = 0; rt < 4; ++rt)
                #pragma unroll
                for (int i = 0; i < 4; ++i) {
                    float h = fmaxf(acc[rt][ct][i] + bb, 0.f);
                    Hs[(rt * 16 + g * 4 + i) * 264 + cb + ct * 16 + lr] = f2bf(h);
                }
        }
    }
    __syncthreads();

    int wrow[4], hoff[4];
    #pragma unroll
    for (int ct = 0; ct < 4; ++ct) wrow[ct] = (cb + ct * 16 + lr) * 256 + g * 8;
    #pragma unroll
    for (int rt = 0; rt < 4; ++rt) hoff[rt] = (rt * 16 + lr) * 264 + g * 8;

    // layer 2 (K=256)
    {
        f32x4 acc[4][4];
        #pragma unroll
        for (int rt = 0; rt < 4; ++rt)
            #pragma unroll
            for (int ct = 0; ct < 4; ++ct) acc[rt][ct] = (f32x4){0.f,0.f,0.f,0.f};
        #pragma unroll 2
        for (int kk = 0; kk < 8; ++kk) {
            bf16x8 bfr[4], afr[4];
            #pragma unroll
            for (int ct = 0; ct < 4; ++ct)
                bfr[ct] = *(const bf16x8*)&W2T[wrow[ct] + kk * 32];
            #pragma unroll
            for (int rt = 0; rt < 4; ++rt)
                afr[rt] = *(const bf16x8*)&Hs[hoff[rt] + kk * 32];
            #pragma unroll
            for (int rt = 0; rt < 4; ++rt)
                #pragma unroll
                for (int ct = 0; ct < 4; ++ct)
                    acc[rt][ct] = mfma16(afr[rt], bfr[ct], acc[rt][ct]);
        }
        __syncthreads();
        #pragma unroll
        for (int ct = 0; ct < 4; ++ct) {
            const float bb = b2[cb + ct * 16 + lr];
            #pragma unroll
            for (int rt = 0; rt < 4; ++rt)
                #pragma unroll
                for (int i = 0; i < 4; ++i) {
                    float h = fmaxf(acc[rt][ct][i] + bb, 0.f);
                    Hs[(rt * 16 + g * 4 + i) * 264 + cb + ct * 16 + lr] = f2bf(h);
                }
        }
    }
    __syncthreads();

    // layer 3 (K=256)
    {
        f32x4 acc[4][4];
        #pragma unroll
        for (int rt = 0; rt < 4; ++rt)
            #pragma unroll
            for (int ct = 0; ct < 4; ++ct) acc[rt][ct] = (f32x4){0.f,0.f,0.f,0.f};
        #pragma unroll 2
        for (int kk = 0; kk < 8; ++kk) {
            bf16x8 bfr[4], afr[4];
            #pragma unroll
            for (int ct = 0; ct < 4; ++ct)
                bfr[ct] = *(const bf16x8*)&W3T[wrow[ct] + kk * 32];
            #pragma unroll
            for (int rt = 0; rt < 4; ++rt)
                afr[rt] = *(const bf16x8*)&Hs[hoff[rt] + kk * 32];
            #pragma unroll
            for (int rt = 0; rt < 4; ++rt)
                #pragma unroll
                for (int ct = 0; ct < 4; ++ct)
                    acc[rt][ct] = mfma16(afr[rt], bfr[ct], acc[rt][ct]);
        }
        #pragma unroll
        for (int ct = 0; ct < 4; ++ct) {
            const int c3 = cb + ct * 16 + lr;
            #pragma unroll
            for (int rt = 0; rt < 4; ++rt)
                #pragma unroll
                for (int i = 0; i < 4; ++i)
                    y[(row0 + rt * 16 + g * 4 + i) * OUTC + DIMX + c3] = acc[rt][ct][i];
        }
    }

    for (int i = tid; i < 512; i += 256) {
        int r = i >> 3, q = i & 7;
        *(float4*)&y[(row0 + r) * OUTC + q * 4] = *(const float4*)&Xf[r * 36 + q * 4];
    }
}

// ---------------------------------------------------------------------------
// K3: fp32 encoder for the 1024 t=0 rows (y0 feeds the scan; needs fp32).
// ---------------------------------------------------------------------------
__global__ __launch_bounds__(256) void enc0_kernel(
    const float* __restrict__ xs,
    const float* __restrict__ W1, const float* __restrict__ b1,
    const float* __restrict__ W2, const float* __restrict__ b2,
    const float* __restrict__ W3,
    float* __restrict__ y)
{
    __shared__ float Xs[8 * 32];
    __shared__ float Hsf[8 * 256];
    const int tid = threadIdx.x;
    const int c   = tid;
    const int n0  = blockIdx.x * 8;

    if (tid < 64) {
        int r = tid >> 3, q = tid & 7;
        *(float4*)&Xs[r * 32 + q * 4] =
            *(const float4*)&xs[(size_t)(n0 + r) * (T_SEQ * DIMX) + q * 4];
    }
    __syncthreads();

    float acc[8];
    {
        float w[32];
        #pragma unroll
        for (int d = 0; d < 32; ++d) w[d] = W1[d * ENCH + c];
        const float bb = b1[c];
        #pragma unroll
        for (int r = 0; r < 8; ++r) {
            float a = bb;
            #pragma unroll
            for (int d4 = 0; d4 < 8; ++d4) {
                float4 xv = *(const float4*)&Xs[r * 32 + d4 * 4];
                a += xv.x * w[d4*4] + xv.y * w[d4*4+1] + xv.z * w[d4*4+2] + xv.w * w[d4*4+3];
            }
            acc[r] = a;
        }
        #pragma unroll
        for (int r = 0; r < 8; ++r) Hsf[r * 256 + c] = fmaxf(acc[r], 0.f);
    }
    __syncthreads();
    {
        const float bb = b2[c];
        #pragma unroll
        for (int r = 0; r < 8; ++r) acc[r] = bb;
        for (int hc = 0; hc < 8; ++hc) {
            float w[32];
            #pragma unroll
            for (int i = 0; i < 32; ++i) w[i] = W2[(hc * 32 + i) * ENCH + c];
            #pragma unroll
            for (int r = 0; r < 8; ++r) {
                float a = acc[r];
                #pragma unroll
                for (int h4 = 0; h4 < 8; ++h4) {
                    float4 hv = *(const float4*)&Hsf[r * 256 + hc * 32 + h4 * 4];
                    a += hv.x * w[h4*4] + hv.y * w[h4*4+1] + hv.z * w[h4*4+2] + hv.w * w[h4*4+3];
                }
                acc[r] = a;
            }
        }
        __syncthreads();
        #pragma unroll
        for (int r = 0; r < 8; ++r) Hsf[r * 256 + c] = fmaxf(acc[r], 0.f);
    }
    __syncthreads();
    {
        #pragma unroll
        for (int r = 0; r < 8; ++r) acc[r] = 0.f;
        for (int hc = 0; hc < 8; ++hc) {
            float w[32];
            #pragma unroll
            for (int i = 0; i < 32; ++i) w[i] = W3[(hc * 32 + i) * LDIM + c];
            #pragma unroll
            for (int r = 0; r < 8; ++r) {
                float a = acc[r];
                #pragma unroll
                for (int h4 = 0; h4 < 8; ++h4) {
                    float4 hv = *(const float4*)&Hsf[r * 256 + hc * 32 + h4 * 4];
                    a += hv.x * w[h4*4] + hv.y * w[h4*4+1] + hv.z * w[h4*4+2] + hv.w * w[h4*4+3];
                }
                acc[r] = a;
            }
        }
    }
    #pragma unroll
    for (int r = 0; r < 8; ++r)
        y[((size_t)(n0 + r) * T_SEQ) * OUTC + DIMX + c] = acc[r];
}

// ---------------------------------------------------------------------------
// K4: scan2 — incremental z^t (ONE expf+sincosf per thread, then 4 FMA/step)
// + fused x_pred readout. Block = one n; 256 threads = latent elements.
// ys staged in LDS with per-row-group rotation rot(t)=((t>>3)&7)*4 so the
// 8 concurrent row-reads in phase 2 hit disjoint bank groups.
// ---------------------------------------------------------------------------
__global__ __launch_bounds__(256) void scan2_kernel(
    const float* __restrict__ xs,
    const float* __restrict__ a_ws, const float* __restrict__ th_ws,
    const float* __restrict__ cwt,   // C_W^T [32d][256l], fp32
    const float* __restrict__ y,     // holds e (fp32 at t=0 rows)
    float* __restrict__ yp)
{
    __shared__ float ys_lds[64][256];   // 64 KB

    const int n = blockIdx.x;
    const int e = threadIdx.x;
    const int k = e >> 1;

    const float* yrow0 = y + (size_t)n * T_SEQ * OUTC + DIMX;
    float2 y0 = *(const float2*)&yrow0[e & ~1];
    const float a  = a_ws [n * NAUX + k];
    const float th = th_ws[n * NAUX + k];

    const float m = expf(a);
    float ss, cc; sincosf(th, &ss, &cc);
    const float cz = m * cc, sz = m * ss;

    float wr = 1.f, wi = 0.f;
    float* ypn = yp + (size_t)n * T_SEQ * OUTC;
    const bool imag = e & 1;

    #pragma unroll 4
    for (int t = 0; t < 64; ++t) {
        float val = imag ? (y0.x * wi + y0.y * wr)
                         : (y0.x * wr - y0.y * wi);
        ypn[(size_t)t * OUTC + DIMX + e] = val;
        ys_lds[t][(e + ((t >> 3) & 7) * 4) & 255] = val;
        float nwr = wr * cz - wi * sz;
        wi = wr * sz + wi * cz;
        wr = nwr;
    }
    __syncthreads();

    // phase 2: x_pred[t][d] = sum_l ys[t][l] * C_W[l][d]  (fp32)
    const int d  = e >> 3;        // 0..31
    const int tg = e & 7;         // 0..7
    const float* cwd = cwt + d * 256;
    const int rot = tg * 4;       // == ((t>>3)&7)*4 for t = tg*8+tt

    #pragma unroll
    for (int tt = 0; tt < 8; ++tt) {
        const int t = tg * 8 + tt;
        float o;
        if (t == 0) {
            o = xs[(size_t)n * T_SEQ * DIMX + d];
        } else {
            float s = 0.f;
            #pragma unroll 8
            for (int l = 0; l < 256; l += 4) {
                const int c0 = (l + rot) & 255;   // contiguous (both %4==0)
                float4 yv = *(const float4*)&ys_lds[t][c0];
                float4 wv = *(const float4*)&cwd[l];
                s += yv.x * wv.x + yv.y * wv.y + yv.z * wv.z + yv.w * wv.w;
            }
            o = s;
        }
        ypn[(size_t)t * OUTC + d] = o;
    }
}

// ---------------------------------------------------------------------------
extern "C" void kernel_launch(void* const* d_in, const int* in_sizes, int n_in,
                              void* d_out, int out_size, void* d_ws, size_t ws_size,
                              hipStream_t stream)
{
    const float* xs   = (const float*)d_in[0];
    const float* eW1  = (const float*)d_in[1];
    const float* eb1  = (const float*)d_in[2];
    const float* eW2  = (const float*)d_in[3];
    const float* eb2  = (const float*)d_in[4];
    const float* eW3  = (const float*)d_in[5];
    const float* aW1  = (const float*)d_in[6];
    const float* ab1  = (const float*)d_in[7];
    const float* aW2  = (const float*)d_in[8];
    const float* ab2  = (const float*)d_in[9];
    const float* aW3  = (const float*)d_in[10];
    const float* C_W  = (const float*)d_in[11];

    float* y  = (float*)d_out;
    float* yp = y + (size_t)N_SEQ * T_SEQ * OUTC;

    // workspace layout
    float* a_ws  = (float*)d_ws;
    float* th_ws = a_ws + (size_t)N_SEQ * NAUX;
    unsigned short* encw = (unsigned short*)(th_ws + (size_t)N_SEQ * NAUX);
    unsigned short* W1T = encw;
    unsigned short* W2T = encw + 8192;
    unsigned short* W3T = encw + 8192 + 65536;
    unsigned short* a1h = encw + CV_ENC;
    unsigned short* a1l = a1h + 524288;
    unsigned short* a2h = a1l + 524288;
    unsigned short* a2l = a2h + 2097152;
    float* cwt = (float*)(a2l + 2097152);

    convw_kernel<<<(CV_ENC + 8192 + 255) / 256, 256, 0, stream>>>(
        eW1, eW2, eW3, C_W, encw, cwt);
    transw_kernel<<<2560, 256, 0, stream>>>(aW1, aW2, a1h, a1l, a2h, a2l);
    auxm_kernel <<<128 * 16, 256, 0, stream>>>(
        xs, a1h, a1l, ab1, a2h, a2l, ab2, aW3, a_ws, th_ws);
    encm_kernel <<<N_SEQ * T_SEQ / 64, 256, 0, stream>>>(xs, W1T, eb1, W2T, eb2, W3T, y);
    enc0_kernel <<<N_SEQ / 8, 256, 0, stream>>>(xs, eW1, eb1, eW2, eb2, eW3, y);
    scan2_kernel<<<N_SEQ, 256, 0, stream>>>(xs, a_ws, th_ws, cwt, y, yp);
}

// Round 5
// 193.835 us; speedup vs baseline: 3.4954x; 1.0841x over previous
//
#include <hip/hip_runtime.h>
#include <math.h>

#define N_SEQ 1024
#define T_SEQ 64
#define DIMX  32
#define LDIM  256
#define NAUX  128
#define AUXH  128
#define ENCH  256
#define OUTC  288           // DIMX + LDIM
#define DT    0.01f

typedef short bf16x8 __attribute__((ext_vector_type(8)));
typedef float f32x4  __attribute__((ext_vector_type(4)));

__device__ __forceinline__ unsigned short f2bf(float f) {
    unsigned u = __builtin_bit_cast(unsigned, f);
    unsigned r = u + 0x7fffu + ((u >> 16) & 1u);   // RNE
    return (unsigned short)(r >> 16);
}
__device__ __forceinline__ float bf2f(unsigned short h) {
    unsigned u = ((unsigned)h) << 16;
    return __builtin_bit_cast(float, u);
}
__device__ __forceinline__ f32x4 mfma16(bf16x8 a, bf16x8 b, f32x4 c) {
    return __builtin_amdgcn_mfma_f32_16x16x32_bf16(a, b, c, 0, 0, 0);
}

// ---------------------------------------------------------------------------
// K0a: encoder weights -> bf16 transposed [col][k]; C_W -> fp32 transposed.
// ---------------------------------------------------------------------------
#define CV_ENC   139264                         // 8192 + 65536 + 65536
__global__ __launch_bounds__(256) void convw_kernel(
    const float* __restrict__ eW1, const float* __restrict__ eW2,
    const float* __restrict__ eW3, const float* __restrict__ C_W,
    unsigned short* __restrict__ encw, float* __restrict__ cwt)
{
    const int idx = blockIdx.x * 256 + threadIdx.x;
    if (idx < 8192) {                          // eW1T [256c][32k]
        int c = idx >> 5, k = idx & 31;
        encw[idx] = f2bf(eW1[k * ENCH + c]);
    } else if (idx < 8192 + 65536) {           // eW2T [256][256]
        int t = idx - 8192; int c = t >> 8, k = t & 255;
        encw[idx] = f2bf(eW2[k * ENCH + c]);
    } else if (idx < CV_ENC) {                 // eW3T [256][256]
        int t = idx - (8192 + 65536); int c = t >> 8, k = t & 255;
        encw[idx] = f2bf(eW3[k * LDIM + c]);
    } else if (idx < CV_ENC + 8192) {          // C_WT [32d][256l] fp32
        int t = idx - CV_ENC; int d = t >> 8, l = t & 255;
        cwt[t] = C_W[l * DIMX + d];
    }
}

// ---------------------------------------------------------------------------
// K0b: aux W1/W2 -> hi/lo bf16 transposed per net, via 32x32 LDS tiles.
// ---------------------------------------------------------------------------
__global__ __launch_bounds__(256) void transw_kernel(
    const float* __restrict__ aW1, const float* __restrict__ aW2,
    unsigned short* __restrict__ a1h, unsigned short* __restrict__ a1l,
    unsigned short* __restrict__ a2h, unsigned short* __restrict__ a2l)
{
    __shared__ float tile[32][33];
    const int b   = blockIdx.x;
    const int tid = threadIdx.x;

    const float* src; unsigned short *dh, *dl; int R, j0, r0;
    if (b < 512) {
        int k = b >> 2; j0 = (b & 3) * 32; r0 = 0; R = 32;
        src = aW1 + (size_t)k * 4096;
        dh = a1h + (size_t)k * 4096; dl = a1l + (size_t)k * 4096;
    } else {
        int bb = b - 512;
        int k = bb >> 4; j0 = ((bb >> 2) & 3) * 32; r0 = (bb & 3) * 32; R = 128;
        src = aW2 + (size_t)k * 16384;
        dh = a2h + (size_t)k * 16384; dl = a2l + (size_t)k * 16384;
    }

    for (int i = tid; i < 1024; i += 256) {
        int rr = i >> 5, jj = i & 31;
        tile[rr][jj] = src[(r0 + rr) * 128 + j0 + jj];
    }
    __syncthreads();
    for (int i = tid; i < 1024; i += 256) {
        int jj = i >> 5, rr = i & 31;
        float w = tile[rr][jj];
        unsigned short hi = f2bf(w);
        int off = (j0 + jj) * R + r0 + rr;
        dh[off] = hi;
        dl[off] = f2bf(w - bf2f(hi));
    }
}

// ---------------------------------------------------------------------------
// K1: aux MLPs via split-bf16 MFMA. LDS diet: h2 reuses h1 hi/lo buffers
// (exact to 2^-18) -> 45KB LDS -> 3 blocks/CU (was 79KB -> 2).
// ---------------------------------------------------------------------------
__global__ __launch_bounds__(256) void auxm_kernel(
    const float* __restrict__ xs,
    const unsigned short* __restrict__ W1h, const unsigned short* __restrict__ W1l,
    const float* __restrict__ b1,
    const unsigned short* __restrict__ W2h, const unsigned short* __restrict__ W2l,
    const float* __restrict__ b2,
    const float* __restrict__ W3,
    float* __restrict__ a_ws, float* __restrict__ th_ws)
{
    const int k   = blockIdx.x >> 4;
    const int n0  = (blockIdx.x & 15) << 6;
    const int tid = threadIdx.x;
    const int wv  = tid >> 6;
    const int ln  = tid & 63;
    const int lr  = ln & 15;
    const int g   = ln >> 4;
    const int cb  = wv * 32;

    __shared__ float          x0s[64][36];   // 9.2 KB
    __shared__ unsigned short h1h[64][136];  // 17.4 KB (reused for h2h)
    __shared__ unsigned short h1l[64][136];  // 17.4 KB (reused for h2l)
    __shared__ float          p3[256];       // 1 KB

    for (int i = tid; i < 512; i += 256) {
        int r = i >> 3, q = i & 7;
        *(float4*)&x0s[r][q * 4] =
            *(const float4*)&xs[(size_t)(n0 + r) * (T_SEQ * DIMX) + q * 4];
    }
    __syncthreads();

    // ---- layer 1: M=64, N=128(32/wave), K=32 ----
    {
        const unsigned short* W1hk = W1h + (size_t)k * 4096;
        const unsigned short* W1lk = W1l + (size_t)k * 4096;
        bf16x8 bh[2], bl[2];
        #pragma unroll
        for (int ct = 0; ct < 2; ++ct) {
            int off = (cb + ct * 16 + lr) * 32 + g * 8;
            bh[ct] = *(const bf16x8*)&W1hk[off];
            bl[ct] = *(const bf16x8*)&W1lk[off];
        }
        f32x4 acc[4][2];
        #pragma unroll
        for (int rt = 0; rt < 4; ++rt) {
            const float* xp = &x0s[rt * 16 + lr][g * 8];
            bf16x8 ah, al;
            #pragma unroll
            for (int e = 0; e < 8; ++e) {
                float x = xp[e];
                unsigned short hi = f2bf(x);
                ah[e] = (short)hi;
                al[e] = (short)f2bf(x - bf2f(hi));
            }
            #pragma unroll
            for (int ct = 0; ct < 2; ++ct) {
                f32x4 z = {0.f, 0.f, 0.f, 0.f};
                z = mfma16(ah, bl[ct], z);
                z = mfma16(al, bh[ct], z);
                acc[rt][ct] = mfma16(ah, bh[ct], z);
            }
        }
        #pragma unroll
        for (int ct = 0; ct < 2; ++ct) {
            const int col = cb + ct * 16 + lr;
            const float bb = b1[k * 128 + col];
            #pragma unroll
            for (int rt = 0; rt < 4; ++rt)
                #pragma unroll
                for (int i = 0; i < 4; ++i) {
                    float h = fmaxf(acc[rt][ct][i] + bb, 0.f);
                    unsigned short hi = f2bf(h);
                    int row = rt * 16 + g * 4 + i;
                    h1h[row][col] = hi;
                    h1l[row][col] = f2bf(h - bf2f(hi));
                }
        }
    }
    __syncthreads();

    // ---- layer 2: M=64, N=128(32/wave), K=128 (4 steps) ----
    {
        const unsigned short* W2hk = W2h + (size_t)k * 16384;
        const unsigned short* W2lk = W2l + (size_t)k * 16384;
        f32x4 acc[4][2];
        #pragma unroll
        for (int rt = 0; rt < 4; ++rt)
            #pragma unroll
            for (int ct = 0; ct < 2; ++ct) acc[rt][ct] = (f32x4){0.f,0.f,0.f,0.f};

        #pragma unroll
        for (int kk = 0; kk < 4; ++kk) {
            bf16x8 bh[2], bl[2], ah[4], al[4];
            #pragma unroll
            for (int ct = 0; ct < 2; ++ct) {
                int off = (cb + ct * 16 + lr) * 128 + kk * 32 + g * 8;
                bh[ct] = *(const bf16x8*)&W2hk[off];
                bl[ct] = *(const bf16x8*)&W2lk[off];
            }
            #pragma unroll
            for (int rt = 0; rt < 4; ++rt) {
                ah[rt] = *(const bf16x8*)&h1h[rt * 16 + lr][kk * 32 + g * 8];
                al[rt] = *(const bf16x8*)&h1l[rt * 16 + lr][kk * 32 + g * 8];
            }
            #pragma unroll
            for (int rt = 0; rt < 4; ++rt)
                #pragma unroll
                for (int ct = 0; ct < 2; ++ct) {
                    f32x4 z = acc[rt][ct];
                    z = mfma16(ah[rt], bl[ct], z);
                    z = mfma16(al[rt], bh[ct], z);
                    acc[rt][ct] = mfma16(ah[rt], bh[ct], z);
                }
        }
        __syncthreads();   // all h1 reads done before overwriting with h2
        #pragma unroll
        for (int ct = 0; ct < 2; ++ct) {
            const int col = cb + ct * 16 + lr;
            const float bb = b2[k * 128 + col];
            #pragma unroll
            for (int rt = 0; rt < 4; ++rt)
                #pragma unroll
                for (int i = 0; i < 4; ++i) {
                    float h = fmaxf(acc[rt][ct][i] + bb, 0.f);
                    unsigned short hi = f2bf(h);
                    int row = rt * 16 + g * 4 + i;
                    h1h[row][col] = hi;           // h2 hi
                    h1l[row][col] = f2bf(h - bf2f(hi));  // h2 lo
                }
        }
    }
    __syncthreads();

    // ---- layer 3: all 256 threads (h halves), LDS combine ----
    {
        const int hh = tid >> 7, r = tid & 127, n = r >> 1, o = r & 1;
        const float* W3k = W3 + (size_t)k * (AUXH * 2);
        float s = 0.f;
        #pragma unroll
        for (int h8 = hh * 64; h8 < hh * 64 + 64; h8 += 8) {
            bf16x8 vh = *(const bf16x8*)&h1h[n][h8];
            bf16x8 vl = *(const bf16x8*)&h1l[n][h8];
            #pragma unroll
            for (int u = 0; u < 8; ++u) {
                float hv = bf2f((unsigned short)vh[u]) + bf2f((unsigned short)vl[u]);
                s += hv * W3k[(h8 + u) * 2 + o];
            }
        }
        p3[tid] = s;
    }
    __syncthreads();
    if (tid < 128) {
        const int n = tid >> 1, o = tid & 1;
        float v = (p3[tid] + p3[tid + 128]) * DT;
        float* dst = o ? th_ws : a_ws;
        dst[(size_t)(n0 + n) * NAUX + k] = v;
    }
}

// ---------------------------------------------------------------------------
// K2: encoder via bf16 MFMA (validated, unchanged).
// ---------------------------------------------------------------------------
__global__ __launch_bounds__(256) void encm_kernel(
    const float* __restrict__ xs,
    const unsigned short* __restrict__ W1T, const float* __restrict__ b1,
    const unsigned short* __restrict__ W2T, const float* __restrict__ b2,
    const unsigned short* __restrict__ W3T,
    float* __restrict__ y)
{
    __shared__ float          Xf[64 * 36];
    __shared__ unsigned short Hs[64 * 264];

    const int tid = threadIdx.x;
    const int wv  = tid >> 6;
    const int ln  = tid & 63;
    const int lr  = ln & 15;
    const int g   = ln >> 4;
    const int cb  = wv * 64;
    const size_t row0 = (size_t)blockIdx.x * 64;

    {
        const float4* src = (const float4*)(xs + row0 * DIMX);
        for (int i = tid; i < 512; i += 256) {
            int r = i >> 3, q = i & 7;
            *(float4*)&Xf[r * 36 + q * 4] = src[i];
        }
    }
    __syncthreads();

    // layer 1 (K=32)
    {
        f32x4 acc[4][4];
        bf16x8 bfr[4], afr[4];
        #pragma unroll
        for (int ct = 0; ct < 4; ++ct)
            bfr[ct] = *(const bf16x8*)&W1T[(cb + ct * 16 + lr) * 32 + g * 8];
        #pragma unroll
        for (int rt = 0; rt < 4; ++rt) {
            const float* xp = &Xf[(rt * 16 + lr) * 36 + g * 8];
            float4 u = *(const float4*)xp;
            float4 v = *(const float4*)(xp + 4);
            bf16x8 t;
            t[0]=(short)f2bf(u.x); t[1]=(short)f2bf(u.y); t[2]=(short)f2bf(u.z); t[3]=(short)f2bf(u.w);
            t[4]=(short)f2bf(v.x); t[5]=(short)f2bf(v.y); t[6]=(short)f2bf(v.z); t[7]=(short)f2bf(v.w);
            afr[rt] = t;
        }
        #pragma unroll
        for (int rt = 0; rt < 4; ++rt)
            #pragma unroll
            for (int ct = 0; ct < 4; ++ct) {
                f32x4 z = {0.f, 0.f, 0.f, 0.f};
                acc[rt][ct] = mfma16(afr[rt], bfr[ct], z);
            }
        #pragma unroll
        for (int ct = 0; ct < 4; ++ct) {
            const float bb = b1[cb + ct * 16 + lr];
            #pragma unroll
            for (int rt = 0; rt < 4; ++rt)
                #pragma unroll
                for (int i = 0; i < 4; ++i) {
                    float h = fmaxf(acc[rt][ct][i] + bb, 0.f);
                    Hs[(rt * 16 + g * 4 + i) * 264 + cb + ct * 16 + lr] = f2bf(h);
                }
        }
    }
    __syncthreads();

    int wrow[4], hoff[4];
    #pragma unroll
    for (int ct = 0; ct < 4; ++ct) wrow[ct] = (cb + ct * 16 + lr) * 256 + g * 8;
    #pragma unroll
    for (int rt = 0; rt < 4; ++rt) hoff[rt] = (rt * 16 + lr) * 264 + g * 8;

    // layer 2 (K=256)
    {
        f32x4 acc[4][4];
        #pragma unroll
        for (int rt = 0; rt < 4; ++rt)
            #pragma unroll
            for (int ct = 0; ct < 4; ++ct) acc[rt][ct] = (f32x4){0.f,0.f,0.f,0.f};
        #pragma unroll 2
        for (int kk = 0; kk < 8; ++kk) {
            bf16x8 bfr[4], afr[4];
            #pragma unroll
            for (int ct = 0; ct < 4; ++ct)
                bfr[ct] = *(const bf16x8*)&W2T[wrow[ct] + kk * 32];
            #pragma unroll
            for (int rt = 0; rt < 4; ++rt)
                afr[rt] = *(const bf16x8*)&Hs[hoff[rt] + kk * 32];
            #pragma unroll
            for (int rt = 0; rt < 4; ++rt)
                #pragma unroll
                for (int ct = 0; ct < 4; ++ct)
                    acc[rt][ct] = mfma16(afr[rt], bfr[ct], acc[rt][ct]);
        }
        __syncthreads();
        #pragma unroll
        for (int ct = 0; ct < 4; ++ct) {
            const float bb = b2[cb + ct * 16 + lr];
            #pragma unroll
            for (int rt = 0; rt < 4; ++rt)
                #pragma unroll
                for (int i = 0; i < 4; ++i) {
                    float h = fmaxf(acc[rt][ct][i] + bb, 0.f);
                    Hs[(rt * 16 + g * 4 + i) * 264 + cb + ct * 16 + lr] = f2bf(h);
                }
        }
    }
    __syncthreads();

    // layer 3 (K=256)
    {
        f32x4 acc[4][4];
        #pragma unroll
        for (int rt = 0; rt < 4; ++rt)
            #pragma unroll
            for (int ct = 0; ct < 4; ++ct) acc[rt][ct] = (f32x4){0.f,0.f,0.f,0.f};
        #pragma unroll 2
        for (int kk = 0; kk < 8; ++kk) {
            bf16x8 bfr[4], afr[4];
            #pragma unroll
            for (int ct = 0; ct < 4; ++ct)
                bfr[ct] = *(const bf16x8*)&W3T[wrow[ct] + kk * 32];
            #pragma unroll
            for (int rt = 0; rt < 4; ++rt)
                afr[rt] = *(const bf16x8*)&Hs[hoff[rt] + kk * 32];
            #pragma unroll
            for (int rt = 0; rt < 4; ++rt)
                #pragma unroll
                for (int ct = 0; ct < 4; ++ct)
                    acc[rt][ct] = mfma16(afr[rt], bfr[ct], acc[rt][ct]);
        }
        #pragma unroll
        for (int ct = 0; ct < 4; ++ct) {
            const int c3 = cb + ct * 16 + lr;
            #pragma unroll
            for (int rt = 0; rt < 4; ++rt)
                #pragma unroll
                for (int i = 0; i < 4; ++i)
                    y[(row0 + rt * 16 + g * 4 + i) * OUTC + DIMX + c3] = acc[rt][ct][i];
        }
    }

    for (int i = tid; i < 512; i += 256) {
        int r = i >> 3, q = i & 7;
        *(float4*)&y[(row0 + r) * OUTC + q * 4] = *(const float4*)&Xf[r * 36 + q * 4];
    }
}

// ---------------------------------------------------------------------------
// K3: fp32 encoder for the 1024 t=0 rows. Now 4 rows/block, 256 blocks
// (1 block/CU instead of 0.5).
// ---------------------------------------------------------------------------
__global__ __launch_bounds__(256) void enc0_kernel(
    const float* __restrict__ xs,
    const float* __restrict__ W1, const float* __restrict__ b1,
    const float* __restrict__ W2, const float* __restrict__ b2,
    const float* __restrict__ W3,
    float* __restrict__ y)
{
    __shared__ float Xs[4 * 32];
    __shared__ float Hsf[4 * 256];
    const int tid = threadIdx.x;
    const int c   = tid;
    const int n0  = blockIdx.x * 4;

    if (tid < 32) {
        int r = tid >> 3, q = tid & 7;
        *(float4*)&Xs[r * 32 + q * 4] =
            *(const float4*)&xs[(size_t)(n0 + r) * (T_SEQ * DIMX) + q * 4];
    }
    __syncthreads();

    float acc[4];
    {
        float w[32];
        #pragma unroll
        for (int d = 0; d < 32; ++d) w[d] = W1[d * ENCH + c];
        const float bb = b1[c];
        #pragma unroll
        for (int r = 0; r < 4; ++r) {
            float a = bb;
            #pragma unroll
            for (int d4 = 0; d4 < 8; ++d4) {
                float4 xv = *(const float4*)&Xs[r * 32 + d4 * 4];
                a += xv.x * w[d4*4] + xv.y * w[d4*4+1] + xv.z * w[d4*4+2] + xv.w * w[d4*4+3];
            }
            acc[r] = a;
        }
        #pragma unroll
        for (int r = 0; r < 4; ++r) Hsf[r * 256 + c] = fmaxf(acc[r], 0.f);
    }
    __syncthreads();
    {
        const float bb = b2[c];
        #pragma unroll
        for (int r = 0; r < 4; ++r) acc[r] = bb;
        for (int hc = 0; hc < 8; ++hc) {
            float w[32];
            #pragma unroll
            for (int i = 0; i < 32; ++i) w[i] = W2[(hc * 32 + i) * ENCH + c];
            #pragma unroll
            for (int r = 0; r < 4; ++r) {
                float a = acc[r];
                #pragma unroll
                for (int h4 = 0; h4 < 8; ++h4) {
                    float4 hv = *(const float4*)&Hsf[r * 256 + hc * 32 + h4 * 4];
                    a += hv.x * w[h4*4] + hv.y * w[h4*4+1] + hv.z * w[h4*4+2] + hv.w * w[h4*4+3];
                }
                acc[r] = a;
            }
        }
        __syncthreads();
        #pragma unroll
        for (int r = 0; r < 4; ++r) Hsf[r * 256 + c] = fmaxf(acc[r], 0.f);
    }
    __syncthreads();
    {
        #pragma unroll
        for (int r = 0; r < 4; ++r) acc[r] = 0.f;
        for (int hc = 0; hc < 8; ++hc) {
            float w[32];
            #pragma unroll
            for (int i = 0; i < 32; ++i) w[i] = W3[(hc * 32 + i) * LDIM + c];
            #pragma unroll
            for (int r = 0; r < 4; ++r) {
                float a = acc[r];
                #pragma unroll
                for (int h4 = 0; h4 < 8; ++h4) {
                    float4 hv = *(const float4*)&Hsf[r * 256 + hc * 32 + h4 * 4];
                    a += hv.x * w[h4*4] + hv.y * w[h4*4+1] + hv.z * w[h4*4+2] + hv.w * w[h4*4+3];
                }
                acc[r] = a;
            }
        }
    }
    #pragma unroll
    for (int r = 0; r < 4; ++r)
        y[((size_t)(n0 + r) * T_SEQ) * OUTC + DIMX + c] = acc[r];
}

// ---------------------------------------------------------------------------
// K4: scan3 — block = (n, 16-t quarter), 4096 blocks, 16 KB LDS.
// Start w = z^(16q) via 4 repeated squarings (+ <=3 uniform muls), then
// 16 incremental complex-mul steps. Fused x_pred readout from LDS.
// ---------------------------------------------------------------------------
__global__ __launch_bounds__(256) void scan3_kernel(
    const float* __restrict__ xs,
    const float* __restrict__ a_ws, const float* __restrict__ th_ws,
    const float* __restrict__ cwt,   // C_W^T [32d][256l], fp32
    const float* __restrict__ y,     // holds e (fp32 at t=0 rows)
    float* __restrict__ yp)
{
    __shared__ float ys_lds[16][256];   // 16 KB

    const int n = blockIdx.x >> 2;
    const int q = blockIdx.x & 3;       // t-quarter: t = q*16 + tl
    const int e = threadIdx.x;
    const int k = e >> 1;

    const float* yrow0 = y + (size_t)n * T_SEQ * OUTC + DIMX;
    float2 y0 = *(const float2*)&yrow0[e & ~1];
    const float a  = a_ws [n * NAUX + k];
    const float th = th_ws[n * NAUX + k];

    const float m = expf(a);
    float ss, cc; sincosf(th, &ss, &cc);
    const float zr = m * cc, zi = m * ss;

    // p = z^16 via 4 squarings
    float pr = zr, pi = zi;
    #pragma unroll
    for (int s2 = 0; s2 < 4; ++s2) {
        float nr = pr * pr - pi * pi;
        pi = 2.f * pr * pi; pr = nr;
    }
    // w = z^(16q)  (q uniform per block, <=3 muls)
    float wr = 1.f, wi = 0.f;
    for (int j = 0; j < q; ++j) {
        float nr = wr * pr - wi * pi;
        wi = wr * pi + wi * pr; wr = nr;
    }

    const bool imag = e & 1;
    float* ypn = yp + (size_t)n * T_SEQ * OUTC;

    #pragma unroll 4
    for (int tl = 0; tl < 16; ++tl) {
        const int t = q * 16 + tl;
        float val = imag ? (y0.x * wi + y0.y * wr)
                         : (y0.x * wr - y0.y * wi);
        ypn[(size_t)t * OUTC + DIMX + e] = val;
        ys_lds[tl][(e + ((tl >> 1) & 7) * 4) & 255] = val;
        float nwr = wr * zr - wi * zi;
        wi = wr * zi + wi * zr;
        wr = nwr;
    }
    __syncthreads();

    // phase 2: x_pred[t][d] = sum_l ys[t][l] * C_W[l][d]
    const int d  = e >> 3;        // 0..31
    const int tg = e & 7;         // 0..7
    const float* cwd = cwt + d * 256;
    const int rot = tg * 4;       // matches write rot for tl = 2*tg + s

    #pragma unroll
    for (int s = 0; s < 2; ++s) {
        const int tl = tg * 2 + s;
        const int t  = q * 16 + tl;
        float o;
        if (t == 0) {
            o = xs[(size_t)n * T_SEQ * DIMX + d];
        } else {
            float sum = 0.f;
            #pragma unroll 8
            for (int l = 0; l < 256; l += 4) {
                const int c0 = (l + rot) & 255;
                float4 yv = *(const float4*)&ys_lds[tl][c0];
                float4 wv = *(const float4*)&cwd[l];
                sum += yv.x * wv.x + yv.y * wv.y + yv.z * wv.z + yv.w * wv.w;
            }
            o = sum;
        }
        ypn[(size_t)t * OUTC + d] = o;
    }
}

// ---------------------------------------------------------------------------
extern "C" void kernel_launch(void* const* d_in, const int* in_sizes, int n_in,
                              void* d_out, int out_size, void* d_ws, size_t ws_size,
                              hipStream_t stream)
{
    const float* xs   = (const float*)d_in[0];
    const float* eW1  = (const float*)d_in[1];
    const float* eb1  = (const float*)d_in[2];
    const float* eW2  = (const float*)d_in[3];
    const float* eb2  = (const float*)d_in[4];
    const float* eW3  = (const float*)d_in[5];
    const float* aW1  = (const float*)d_in[6];
    const float* ab1  = (const float*)d_in[7];
    const float* aW2  = (const float*)d_in[8];
    const float* ab2  = (const float*)d_in[9];
    const float* aW3  = (const float*)d_in[10];
    const float* C_W  = (const float*)d_in[11];

    float* y  = (float*)d_out;
    float* yp = y + (size_t)N_SEQ * T_SEQ * OUTC;

    // workspace layout
    float* a_ws  = (float*)d_ws;
    float* th_ws = a_ws + (size_t)N_SEQ * NAUX;
    unsigned short* encw = (unsigned short*)(th_ws + (size_t)N_SEQ * NAUX);
    unsigned short* W1T = encw;
    unsigned short* W2T = encw + 8192;
    unsigned short* W3T = encw + 8192 + 65536;
    unsigned short* a1h = encw + CV_ENC;
    unsigned short* a1l = a1h + 524288;
    unsigned short* a2h = a1l + 524288;
    unsigned short* a2l = a2h + 2097152;
    float* cwt = (float*)(a2l + 2097152);

    convw_kernel<<<(CV_ENC + 8192 + 255) / 256, 256, 0, stream>>>(
        eW1, eW2, eW3, C_W, encw, cwt);
    transw_kernel<<<2560, 256, 0, stream>>>(aW1, aW2, a1h, a1l, a2h, a2l);
    auxm_kernel <<<128 * 16, 256, 0, stream>>>(
        xs, a1h, a1l, ab1, a2h, a2l, ab2, aW3, a_ws, th_ws);
    encm_kernel <<<N_SEQ * T_SEQ / 64, 256, 0, stream>>>(xs, W1T, eb1, W2T, eb2, W3T, y);
    enc0_kernel <<<N_SEQ / 4, 256, 0, stream>>>(xs, eW1, eb1, eW2, eb2, eW3, y);
    scan3_kernel<<<N_SEQ * 4, 256, 0, stream>>>(xs, a_ws, th_ws, cwt, y, yp);
}

// Round 7
// 190.870 us; speedup vs baseline: 3.5497x; 1.0155x over previous
//
#include <hip/hip_runtime.h>
#include <math.h>

#define N_SEQ 1024
#define T_SEQ 64
#define DIMX  32
#define LDIM  256
#define NAUX  128
#define AUXH  128
#define ENCH  256
#define OUTC  288           // DIMX + LDIM
#define DT    0.01f

typedef short bf16x8 __attribute__((ext_vector_type(8)));
typedef float f32x4  __attribute__((ext_vector_type(4)));

__device__ __forceinline__ unsigned short f2bf(float f) {
    unsigned u = __builtin_bit_cast(unsigned, f);
    unsigned r = u + 0x7fffu + ((u >> 16) & 1u);   // RNE
    return (unsigned short)(r >> 16);
}
__device__ __forceinline__ float bf2f(unsigned short h) {
    unsigned u = ((unsigned)h) << 16;
    return __builtin_bit_cast(float, u);
}
__device__ __forceinline__ f32x4 mfma16(bf16x8 a, bf16x8 b, f32x4 c) {
    return __builtin_amdgcn_mfma_f32_16x16x32_bf16(a, b, c, 0, 0, 0);
}

// ---------------------------------------------------------------------------
// K0: merged prep — blocks [0,576): encoder weights -> bf16 T + C_W^T fp32;
// blocks [576,3136): aux W1/W2 -> hi/lo bf16 T via 32x32 LDS tiles.
// ---------------------------------------------------------------------------
#define CV_ENC   139264                         // 8192 + 65536 + 65536
#define PREP_CONV_BLOCKS 576                    // (CV_ENC + 8192) / 256
__global__ __launch_bounds__(256) void prep_kernel(
    const float* __restrict__ eW1, const float* __restrict__ eW2,
    const float* __restrict__ eW3, const float* __restrict__ C_W,
    const float* __restrict__ aW1, const float* __restrict__ aW2,
    unsigned short* __restrict__ encw, float* __restrict__ cwt,
    unsigned short* __restrict__ a1h, unsigned short* __restrict__ a1l,
    unsigned short* __restrict__ a2h, unsigned short* __restrict__ a2l)
{
    __shared__ float tile[32][33];
    const int b   = blockIdx.x;
    const int tid = threadIdx.x;

    if (b < PREP_CONV_BLOCKS) {
        const int idx = b * 256 + tid;
        if (idx < 8192) {                          // eW1T [256c][32k]
            int c = idx >> 5, k = idx & 31;
            encw[idx] = f2bf(eW1[k * ENCH + c]);
        } else if (idx < 8192 + 65536) {           // eW2T [256][256]
            int t = idx - 8192; int c = t >> 8, k = t & 255;
            encw[idx] = f2bf(eW2[k * ENCH + c]);
        } else if (idx < CV_ENC) {                 // eW3T [256][256]
            int t = idx - (8192 + 65536); int c = t >> 8, k = t & 255;
            encw[idx] = f2bf(eW3[k * LDIM + c]);
        } else if (idx < CV_ENC + 8192) {          // C_WT [32d][256l] fp32
            int t = idx - CV_ENC; int d = t >> 8, l = t & 255;
            cwt[t] = C_W[l * DIMX + d];
        }
        return;
    }

    const int bb0 = b - PREP_CONV_BLOCKS;
    const float* src; unsigned short *dh, *dl; int R, j0, r0;
    if (bb0 < 512) {
        int k = bb0 >> 2; j0 = (bb0 & 3) * 32; r0 = 0; R = 32;
        src = aW1 + (size_t)k * 4096;
        dh = a1h + (size_t)k * 4096; dl = a1l + (size_t)k * 4096;
    } else {
        int bb = bb0 - 512;
        int k = bb >> 4; j0 = ((bb >> 2) & 3) * 32; r0 = (bb & 3) * 32; R = 128;
        src = aW2 + (size_t)k * 16384;
        dh = a2h + (size_t)k * 16384; dl = a2l + (size_t)k * 16384;
    }

    for (int i = tid; i < 1024; i += 256) {
        int rr = i >> 5, jj = i & 31;
        tile[rr][jj] = src[(r0 + rr) * 128 + j0 + jj];
    }
    __syncthreads();
    for (int i = tid; i < 1024; i += 256) {
        int jj = i >> 5, rr = i & 31;
        float w = tile[rr][jj];
        unsigned short hi = f2bf(w);
        int off = (j0 + jj) * R + r0 + rr;
        dh[off] = hi;
        dl[off] = f2bf(w - bf2f(hi));
    }
}

// ---------------------------------------------------------------------------
// K1: aux MLPs via split-bf16 MFMA (R6 version — under bisect test).
// ---------------------------------------------------------------------------
__global__ __launch_bounds__(256) void auxm_kernel(
    const float* __restrict__ xs,
    const unsigned short* __restrict__ W1h, const unsigned short* __restrict__ W1l,
    const float* __restrict__ b1,
    const unsigned short* __restrict__ W2h, const unsigned short* __restrict__ W2l,
    const float* __restrict__ b2,
    const float* __restrict__ W3,
    float* __restrict__ a_ws, float* __restrict__ th_ws)
{
    const int k   = blockIdx.x >> 4;
    const int n0  = (blockIdx.x & 15) << 6;
    const int tid = threadIdx.x;
    const int wv  = tid >> 6;
    const int ln  = tid & 63;
    const int lr  = ln & 15;
    const int g   = ln >> 4;
    const int cb  = wv * 32;

    __shared__ unsigned short x0h[64][40];
    __shared__ unsigned short x0l[64][40];
    __shared__ unsigned short h1h[64][136];
    __shared__ unsigned short h1l[64][136];
    __shared__ float          p3[256];

    for (int i = tid; i < 512; i += 256) {
        int r = i >> 3, qd = i & 7;
        float4 v = *(const float4*)&xs[(size_t)(n0 + r) * (T_SEQ * DIMX) + qd * 4];
        short4 hs, ls;
        float vv[4] = {v.x, v.y, v.z, v.w};
        short* hp = (short*)&hs; short* lp = (short*)&ls;
        #pragma unroll
        for (int u = 0; u < 4; ++u) {
            unsigned short hi = f2bf(vv[u]);
            hp[u] = (short)hi;
            lp[u] = (short)f2bf(vv[u] - bf2f(hi));
        }
        *(short4*)&x0h[r][qd * 4] = hs;
        *(short4*)&x0l[r][qd * 4] = ls;
    }
    __syncthreads();

    // ---- layer 1 ----
    {
        const unsigned short* W1hk = W1h + (size_t)k * 4096;
        const unsigned short* W1lk = W1l + (size_t)k * 4096;
        bf16x8 bh[2], bl[2];
        #pragma unroll
        for (int ct = 0; ct < 2; ++ct) {
            int off = (cb + ct * 16 + lr) * 32 + g * 8;
            bh[ct] = *(const bf16x8*)&W1hk[off];
            bl[ct] = *(const bf16x8*)&W1lk[off];
        }
        f32x4 acc[4][2];
        #pragma unroll
        for (int rt = 0; rt < 4; ++rt) {
            bf16x8 ah = *(const bf16x8*)&x0h[rt * 16 + lr][g * 8];
            bf16x8 al = *(const bf16x8*)&x0l[rt * 16 + lr][g * 8];
            #pragma unroll
            for (int ct = 0; ct < 2; ++ct) {
                f32x4 z = {0.f, 0.f, 0.f, 0.f};
                z = mfma16(ah, bl[ct], z);
                z = mfma16(al, bh[ct], z);
                acc[rt][ct] = mfma16(ah, bh[ct], z);
            }
        }
        #pragma unroll
        for (int ct = 0; ct < 2; ++ct) {
            const int col = cb + ct * 16 + lr;
            const float bb = b1[k * 128 + col];
            #pragma unroll
            for (int rt = 0; rt < 4; ++rt)
                #pragma unroll
                for (int i = 0; i < 4; ++i) {
                    float h = fmaxf(acc[rt][ct][i] + bb, 0.f);
                    unsigned short hi = f2bf(h);
                    int row = rt * 16 + g * 4 + i;
                    h1h[row][col] = hi;
                    h1l[row][col] = f2bf(h - bf2f(hi));
                }
        }
    }
    __syncthreads();

    // ---- layer 2 ----
    {
        const unsigned short* W2hk = W2h + (size_t)k * 16384;
        const unsigned short* W2lk = W2l + (size_t)k * 16384;
        f32x4 acc[4][2];
        #pragma unroll
        for (int rt = 0; rt < 4; ++rt)
            #pragma unroll
            for (int ct = 0; ct < 2; ++ct) acc[rt][ct] = (f32x4){0.f,0.f,0.f,0.f};

        #pragma unroll
        for (int kk = 0; kk < 4; ++kk) {
            bf16x8 bh[2], bl[2], ah[4], al[4];
            #pragma unroll
            for (int ct = 0; ct < 2; ++ct) {
                int off = (cb + ct * 16 + lr) * 128 + kk * 32 + g * 8;
                bh[ct] = *(const bf16x8*)&W2hk[off];
                bl[ct] = *(const bf16x8*)&W2lk[off];
            }
            #pragma unroll
            for (int rt = 0; rt < 4; ++rt) {
                ah[rt] = *(const bf16x8*)&h1h[rt * 16 + lr][kk * 32 + g * 8];
                al[rt] = *(const bf16x8*)&h1l[rt * 16 + lr][kk * 32 + g * 8];
            }
            #pragma unroll
            for (int rt = 0; rt < 4; ++rt)
                #pragma unroll
                for (int ct = 0; ct < 2; ++ct) {
                    f32x4 z = acc[rt][ct];
                    z = mfma16(ah[rt], bl[ct], z);
                    z = mfma16(al[rt], bh[ct], z);
                    acc[rt][ct] = mfma16(ah[rt], bh[ct], z);
                }
        }
        __syncthreads();
        #pragma unroll
        for (int ct = 0; ct < 2; ++ct) {
            const int col = cb + ct * 16 + lr;
            const float bb = b2[k * 128 + col];
            #pragma unroll
            for (int rt = 0; rt < 4; ++rt)
                #pragma unroll
                for (int i = 0; i < 4; ++i) {
                    float h = fmaxf(acc[rt][ct][i] + bb, 0.f);
                    unsigned short hi = f2bf(h);
                    int row = rt * 16 + g * 4 + i;
                    h1h[row][col] = hi;
                    h1l[row][col] = f2bf(h - bf2f(hi));
                }
        }
    }
    __syncthreads();

    // ---- layer 3 ----
    {
        const int hh = tid >> 7, r = tid & 127, n = r >> 1, o = r & 1;
        const float* W3k = W3 + (size_t)k * (AUXH * 2);
        float s = 0.f;
        #pragma unroll
        for (int h8 = hh * 64; h8 < hh * 64 + 64; h8 += 8) {
            bf16x8 vh = *(const bf16x8*)&h1h[n][h8];
            bf16x8 vl = *(const bf16x8*)&h1l[n][h8];
            #pragma unroll
            for (int u = 0; u < 8; ++u) {
                float hv = bf2f((unsigned short)vh[u]) + bf2f((unsigned short)vl[u]);
                s += hv * W3k[(h8 + u) * 2 + o];
            }
        }
        p3[tid] = s;
    }
    __syncthreads();
    if (tid < 128) {
        const int n = tid >> 1, o = tid & 1;
        float v = (p3[tid] + p3[tid + 128]) * DT;
        float* dst = o ? th_ws : a_ws;
        dst[(size_t)(n0 + n) * NAUX + k] = v;
    }
}

// ---------------------------------------------------------------------------
// K2: encoder via bf16 MFMA (validated, unchanged).
// ---------------------------------------------------------------------------
__global__ __launch_bounds__(256) void encm_kernel(
    const float* __restrict__ xs,
    const unsigned short* __restrict__ W1T, const float* __restrict__ b1,
    const unsigned short* __restrict__ W2T, const float* __restrict__ b2,
    const unsigned short* __restrict__ W3T,
    float* __restrict__ y)
{
    __shared__ float          Xf[64 * 36];
    __shared__ unsigned short Hs[64 * 264];

    const int tid = threadIdx.x;
    const int wv  = tid >> 6;
    const int ln  = tid & 63;
    const int lr  = ln & 15;
    const int g   = ln >> 4;
    const int cb  = wv * 64;
    const size_t row0 = (size_t)blockIdx.x * 64;

    {
        const float4* src = (const float4*)(xs + row0 * DIMX);
        for (int i = tid; i < 512; i += 256) {
            int r = i >> 3, q = i & 7;
            *(float4*)&Xf[r * 36 + q * 4] = src[i];
        }
    }
    __syncthreads();

    // layer 1 (K=32)
    {
        f32x4 acc[4][4];
        bf16x8 bfr[4], afr[4];
        #pragma unroll
        for (int ct = 0; ct < 4; ++ct)
            bfr[ct] = *(const bf16x8*)&W1T[(cb + ct * 16 + lr) * 32 + g * 8];
        #pragma unroll
        for (int rt = 0; rt < 4; ++rt) {
            const float* xp = &Xf[(rt * 16 + lr) * 36 + g * 8];
            float4 u = *(const float4*)xp;
            float4 v = *(const float4*)(xp + 4);
            bf16x8 t;
            t[0]=(short)f2bf(u.x); t[1]=(short)f2bf(u.y); t[2]=(short)f2bf(u.z); t[3]=(short)f2bf(u.w);
            t[4]=(short)f2bf(v.x); t[5]=(short)f2bf(v.y); t[6]=(short)f2bf(v.z); t[7]=(short)f2bf(v.w);
            afr[rt] = t;
        }
        #pragma unroll
        for (int rt = 0; rt < 4; ++rt)
            #pragma unroll
            for (int ct = 0; ct < 4; ++ct) {
                f32x4 z = {0.f, 0.f, 0.f, 0.f};
                acc[rt][ct] = mfma16(afr[rt], bfr[ct], z);
            }
        #pragma unroll
        for (int ct = 0; ct < 4; ++ct) {
            const float bb = b1[cb + ct * 16 + lr];
            #pragma unroll
            for (int rt = 0; rt < 4; ++rt)
                #pragma unroll
                for (int i = 0; i < 4; ++i) {
                    float h = fmaxf(acc[rt][ct][i] + bb, 0.f);
                    Hs[(rt * 16 + g * 4 + i) * 264 + cb + ct * 16 + lr] = f2bf(h);
                }
        }
    }
    __syncthreads();

    int wrow[4], hoff[4];
    #pragma unroll
    for (int ct = 0; ct < 4; ++ct) wrow[ct] = (cb + ct * 16 + lr) * 256 + g * 8;
    #pragma unroll
    for (int rt = 0; rt < 4; ++rt) hoff[rt] = (rt * 16 + lr) * 264 + g * 8;

    // layer 2 (K=256)
    {
        f32x4 acc[4][4];
        #pragma unroll
        for (int rt = 0; rt < 4; ++rt)
            #pragma unroll
            for (int ct = 0; ct < 4; ++ct) acc[rt][ct] = (f32x4){0.f,0.f,0.f,0.f};
        #pragma unroll 2
        for (int kk = 0; kk < 8; ++kk) {
            bf16x8 bfr[4], afr[4];
            #pragma unroll
            for (int ct = 0; ct < 4; ++ct)
                bfr[ct] = *(const bf16x8*)&W2T[wrow[ct] + kk * 32];
            #pragma unroll
            for (int rt = 0; rt < 4; ++rt)
                afr[rt] = *(const bf16x8*)&Hs[hoff[rt] + kk * 32];
            #pragma unroll
            for (int rt = 0; rt < 4; ++rt)
                #pragma unroll
                for (int ct = 0; ct < 4; ++ct)
                    acc[rt][ct] = mfma16(afr[rt], bfr[ct], acc[rt][ct]);
        }
        __syncthreads();
        #pragma unroll
        for (int ct = 0; ct < 4; ++ct) {
            const float bb = b2[cb + ct * 16 + lr];
            #pragma unroll
            for (int rt = 0; rt < 4; ++rt)
                #pragma unroll
                for (int i = 0; i < 4; ++i) {
                    float h = fmaxf(acc[rt][ct][i] + bb, 0.f);
                    Hs[(rt * 16 + g * 4 + i) * 264 + cb + ct * 16 + lr] = f2bf(h);
                }
        }
    }
    __syncthreads();

    // layer 3 (K=256)
    {
        f32x4 acc[4][4];
        #pragma unroll
        for (int rt = 0; rt < 4; ++rt)
            #pragma unroll
            for (int ct = 0; ct < 4; ++ct) acc[rt][ct] = (f32x4){0.f,0.f,0.f,0.f};
        #pragma unroll 2
        for (int kk = 0; kk < 8; ++kk) {
            bf16x8 bfr[4], afr[4];
            #pragma unroll
            for (int ct = 0; ct < 4; ++ct)
                bfr[ct] = *(const bf16x8*)&W3T[wrow[ct] + kk * 32];
            #pragma unroll
            for (int rt = 0; rt < 4; ++rt)
                afr[rt] = *(const bf16x8*)&Hs[hoff[rt] + kk * 32];
            #pragma unroll
            for (int rt = 0; rt < 4; ++rt)
                #pragma unroll
                for (int ct = 0; ct < 4; ++ct)
                    acc[rt][ct] = mfma16(afr[rt], bfr[ct], acc[rt][ct]);
        }
        #pragma unroll
        for (int ct = 0; ct < 4; ++ct) {
            const int c3 = cb + ct * 16 + lr;
            #pragma unroll
            for (int rt = 0; rt < 4; ++rt)
                #pragma unroll
                for (int i = 0; i < 4; ++i)
                    y[(row0 + rt * 16 + g * 4 + i) * OUTC + DIMX + c3] = acc[rt][ct][i];
        }
    }

    for (int i = tid; i < 512; i += 256) {
        int r = i >> 3, q = i & 7;
        *(float4*)&y[(row0 + r) * OUTC + q * 4] = *(const float4*)&Xf[r * 36 + q * 4];
    }
}

// ---------------------------------------------------------------------------
// K3: fp32 encoder for the 1024 t=0 rows (y0 precision). 4 rows/block.
// ---------------------------------------------------------------------------
__global__ __launch_bounds__(256) void enc0_kernel(
    const float* __restrict__ xs,
    const float* __restrict__ W1, const float* __restrict__ b1,
    const float* __restrict__ W2, const float* __restrict__ b2,
    const float* __restrict__ W3,
    float* __restrict__ y)
{
    __shared__ float Xs[4 * 32];
    __shared__ float Hsf[4 * 256];
    const int tid = threadIdx.x;
    const int c   = tid;
    const int n0  = blockIdx.x * 4;

    if (tid < 32) {
        int r = tid >> 3, q = tid & 7;
        *(float4*)&Xs[r * 32 + q * 4] =
            *(const float4*)&xs[(size_t)(n0 + r) * (T_SEQ * DIMX) + q * 4];
    }
    __syncthreads();

    float acc[4];
    {
        float w[32];
        #pragma unroll
        for (int d = 0; d < 32; ++d) w[d] = W1[d * ENCH + c];
        const float bb = b1[c];
        #pragma unroll
        for (int r = 0; r < 4; ++r) {
            float a = bb;
            #pragma unroll
            for (int d4 = 0; d4 < 8; ++d4) {
                float4 xv = *(const float4*)&Xs[r * 32 + d4 * 4];
                a += xv.x * w[d4*4] + xv.y * w[d4*4+1] + xv.z * w[d4*4+2] + xv.w * w[d4*4+3];
            }
            acc[r] = a;
        }
        #pragma unroll
        for (int r = 0; r < 4; ++r) Hsf[r * 256 + c] = fmaxf(acc[r], 0.f);
    }
    __syncthreads();
    {
        const float bb = b2[c];
        #pragma unroll
        for (int r = 0; r < 4; ++r) acc[r] = bb;
        for (int hc = 0; hc < 8; ++hc) {
            float w[32];
            #pragma unroll
            for (int i = 0; i < 32; ++i) w[i] = W2[(hc * 32 + i) * ENCH + c];
            #pragma unroll
            for (int r = 0; r < 4; ++r) {
                float a = acc[r];
                #pragma unroll
                for (int h4 = 0; h4 < 8; ++h4) {
                    float4 hv = *(const float4*)&Hsf[r * 256 + hc * 32 + h4 * 4];
                    a += hv.x * w[h4*4] + hv.y * w[h4*4+1] + hv.z * w[h4*4+2] + hv.w * w[h4*4+3];
                }
                acc[r] = a;
            }
        }
        __syncthreads();
        #pragma unroll
        for (int r = 0; r < 4; ++r) Hsf[r * 256 + c] = fmaxf(acc[r], 0.f);
    }
    __syncthreads();
    {
        #pragma unroll
        for (int r = 0; r < 4; ++r) acc[r] = 0.f;
        for (int hc = 0; hc < 8; ++hc) {
            float w[32];
            #pragma unroll
            for (int i = 0; i < 32; ++i) w[i] = W3[(hc * 32 + i) * LDIM + c];
            #pragma unroll
            for (int r = 0; r < 4; ++r) {
                float a = acc[r];
                #pragma unroll
                for (int h4 = 0; h4 < 8; ++h4) {
                    float4 hv = *(const float4*)&Hsf[r * 256 + hc * 32 + h4 * 4];
                    a += hv.x * w[h4*4] + hv.y * w[h4*4+1] + hv.z * w[h4*4+2] + hv.w * w[h4*4+3];
                }
                acc[r] = a;
            }
        }
    }
    #pragma unroll
    for (int r = 0; r < 4; ++r)
        y[((size_t)(n0 + r) * T_SEQ) * OUTC + DIMX + c] = acc[r];
}

// ---------------------------------------------------------------------------
// K4: scan3 (R5-proven) — block = (n, 16-t quarter), fp32 broadcast readout.
// ---------------------------------------------------------------------------
__global__ __launch_bounds__(256) void scan3_kernel(
    const float* __restrict__ xs,
    const float* __restrict__ a_ws, const float* __restrict__ th_ws,
    const float* __restrict__ cwt,   // C_W^T [32d][256l], fp32
    const float* __restrict__ y,
    float* __restrict__ yp)
{
    __shared__ float ys_lds[16][256];   // 16 KB

    const int n = blockIdx.x >> 2;
    const int q = blockIdx.x & 3;
    const int e = threadIdx.x;
    const int k = e >> 1;

    const float* yrow0 = y + (size_t)n * T_SEQ * OUTC + DIMX;
    float2 y0 = *(const float2*)&yrow0[e & ~1];
    const float a  = a_ws [n * NAUX + k];
    const float th = th_ws[n * NAUX + k];

    const float m = expf(a);
    float ss, cc; sincosf(th, &ss, &cc);
    const float zr = m * cc, zi = m * ss;

    float pr = zr, pi = zi;
    #pragma unroll
    for (int s2 = 0; s2 < 4; ++s2) {
        float nr = pr * pr - pi * pi;
        pi = 2.f * pr * pi; pr = nr;
    }
    float wr = 1.f, wi = 0.f;
    for (int j = 0; j < q; ++j) {
        float nr = wr * pr - wi * pi;
        wi = wr * pi + wi * pr; wr = nr;
    }

    const bool imag = e & 1;
    float* ypn = yp + (size_t)n * T_SEQ * OUTC;

    #pragma unroll 4
    for (int tl = 0; tl < 16; ++tl) {
        const int t = q * 16 + tl;
        float val = imag ? (y0.x * wi + y0.y * wr)
                         : (y0.x * wr - y0.y * wi);
        ypn[(size_t)t * OUTC + DIMX + e] = val;
        ys_lds[tl][(e + ((tl >> 1) & 7) * 4) & 255] = val;
        float nwr = wr * zr - wi * zi;
        wi = wr * zi + wi * zr;
        wr = nwr;
    }
    __syncthreads();

    const int d  = e >> 3;
    const int tg = e & 7;
    const float* cwd = cwt + d * 256;
    const int rot = tg * 4;

    #pragma unroll
    for (int s = 0; s < 2; ++s) {
        const int tl = tg * 2 + s;
        const int t  = q * 16 + tl;
        float o;
        if (t == 0) {
            o = xs[(size_t)n * T_SEQ * DIMX + d];
        } else {
            float sum = 0.f;
            #pragma unroll 8
            for (int l = 0; l < 256; l += 4) {
                const int c0 = (l + rot) & 255;
                float4 yv = *(const float4*)&ys_lds[tl][c0];
                float4 wv = *(const float4*)&cwd[l];
                sum += yv.x * wv.x + yv.y * wv.y + yv.z * wv.z + yv.w * wv.w;
            }
            o = sum;
        }
        ypn[(size_t)t * OUTC + d] = o;
    }
}

// ---------------------------------------------------------------------------
extern "C" void kernel_launch(void* const* d_in, const int* in_sizes, int n_in,
                              void* d_out, int out_size, void* d_ws, size_t ws_size,
                              hipStream_t stream)
{
    const float* xs   = (const float*)d_in[0];
    const float* eW1  = (const float*)d_in[1];
    const float* eb1  = (const float*)d_in[2];
    const float* eW2  = (const float*)d_in[3];
    const float* eb2  = (const float*)d_in[4];
    const float* eW3  = (const float*)d_in[5];
    const float* aW1  = (const float*)d_in[6];
    const float* ab1  = (const float*)d_in[7];
    const float* aW2  = (const float*)d_in[8];
    const float* ab2  = (const float*)d_in[9];
    const float* aW3  = (const float*)d_in[10];
    const float* C_W  = (const float*)d_in[11];

    float* y  = (float*)d_out;
    float* yp = y + (size_t)N_SEQ * T_SEQ * OUTC;

    // workspace layout (identical to R5)
    float* a_ws  = (float*)d_ws;
    float* th_ws = a_ws + (size_t)N_SEQ * NAUX;
    unsigned short* encw = (unsigned short*)(th_ws + (size_t)N_SEQ * NAUX);
    unsigned short* W1T = encw;
    unsigned short* W2T = encw + 8192;
    unsigned short* W3T = encw + 8192 + 65536;
    unsigned short* a1h = encw + CV_ENC;
    unsigned short* a1l = a1h + 524288;
    unsigned short* a2h = a1l + 524288;
    unsigned short* a2l = a2h + 2097152;
    float* cwt = (float*)(a2l + 2097152);

    prep_kernel<<<PREP_CONV_BLOCKS + 2560, 256, 0, stream>>>(
        eW1, eW2, eW3, C_W, aW1, aW2, encw, cwt, a1h, a1l, a2h, a2l);
    auxm_kernel <<<128 * 16, 256, 0, stream>>>(
        xs, a1h, a1l, ab1, a2h, a2l, ab2, aW3, a_ws, th_ws);
    encm_kernel <<<N_SEQ * T_SEQ / 64, 256, 0, stream>>>(xs, W1T, eb1, W2T, eb2, W3T, y);
    enc0_kernel <<<N_SEQ / 4, 256, 0, stream>>>(xs, eW1, eb1, eW2, eb2, eW3, y);
    scan3_kernel<<<N_SEQ * 4, 256, 0, stream>>>(xs, a_ws, th_ws, cwt, y, yp);
}

// Round 8
// 161.212 us; speedup vs baseline: 4.2027x; 1.1840x over previous
//
#include <hip/hip_runtime.h>
#include <math.h>

#define N_SEQ 1024
#define T_SEQ 64
#define DIMX  32
#define LDIM  256
#define NAUX  128
#define AUXH  128
#define ENCH  256
#define OUTC  288           // DIMX + LDIM
#define DT    0.01f

typedef short bf16x8 __attribute__((ext_vector_type(8)));
typedef float f32x4  __attribute__((ext_vector_type(4)));

__device__ __forceinline__ unsigned short f2bf(float f) {
    unsigned u = __builtin_bit_cast(unsigned, f);
    unsigned r = u + 0x7fffu + ((u >> 16) & 1u);   // RNE
    return (unsigned short)(r >> 16);
}
__device__ __forceinline__ float bf2f(unsigned short h) {
    unsigned u = ((unsigned)h) << 16;
    return __builtin_bit_cast(float, u);
}
__device__ __forceinline__ f32x4 mfma16(bf16x8 a, bf16x8 b, f32x4 c) {
    return __builtin_amdgcn_mfma_f32_16x16x32_bf16(a, b, c, 0, 0, 0);
}

// ---------------------------------------------------------------------------
// K0: merged prep — blocks [0,576): encoder weights -> bf16 T + C_W^T fp32;
// blocks [576,3136): aux W1/W2 -> hi/lo bf16 T via 32x32 LDS tiles.
// ---------------------------------------------------------------------------
#define CV_ENC   139264                         // 8192 + 65536 + 65536
#define PREP_CONV_BLOCKS 576                    // (CV_ENC + 8192) / 256
__global__ __launch_bounds__(256) void prep_kernel(
    const float* __restrict__ eW1, const float* __restrict__ eW2,
    const float* __restrict__ eW3, const float* __restrict__ C_W,
    const float* __restrict__ aW1, const float* __restrict__ aW2,
    unsigned short* __restrict__ encw, float* __restrict__ cwt,
    unsigned short* __restrict__ a1h, unsigned short* __restrict__ a1l,
    unsigned short* __restrict__ a2h, unsigned short* __restrict__ a2l)
{
    __shared__ float tile[32][33];
    const int b   = blockIdx.x;
    const int tid = threadIdx.x;

    if (b < PREP_CONV_BLOCKS) {
        const int idx = b * 256 + tid;
        if (idx < 8192) {                          // eW1T [256c][32k]
            int c = idx >> 5, k = idx & 31;
            encw[idx] = f2bf(eW1[k * ENCH + c]);
        } else if (idx < 8192 + 65536) {           // eW2T [256][256]
            int t = idx - 8192; int c = t >> 8, k = t & 255;
            encw[idx] = f2bf(eW2[k * ENCH + c]);
        } else if (idx < CV_ENC) {                 // eW3T [256][256]
            int t = idx - (8192 + 65536); int c = t >> 8, k = t & 255;
            encw[idx] = f2bf(eW3[k * LDIM + c]);
        } else if (idx < CV_ENC + 8192) {          // C_WT [32d][256l] fp32
            int t = idx - CV_ENC; int d = t >> 8, l = t & 255;
            cwt[t] = C_W[l * DIMX + d];
        }
        return;
    }

    const int bb0 = b - PREP_CONV_BLOCKS;
    const float* src; unsigned short *dh, *dl; int R, j0, r0;
    if (bb0 < 512) {
        int k = bb0 >> 2; j0 = (bb0 & 3) * 32; r0 = 0; R = 32;
        src = aW1 + (size_t)k * 4096;
        dh = a1h + (size_t)k * 4096; dl = a1l + (size_t)k * 4096;
    } else {
        int bb = bb0 - 512;
        int k = bb >> 4; j0 = ((bb >> 2) & 3) * 32; r0 = (bb & 3) * 32; R = 128;
        src = aW2 + (size_t)k * 16384;
        dh = a2h + (size_t)k * 16384; dl = a2l + (size_t)k * 16384;
    }

    for (int i = tid; i < 1024; i += 256) {
        int rr = i >> 5, jj = i & 31;
        tile[rr][jj] = src[(r0 + rr) * 128 + j0 + jj];
    }
    __syncthreads();
    for (int i = tid; i < 1024; i += 256) {
        int jj = i >> 5, rr = i & 31;
        float w = tile[rr][jj];
        unsigned short hi = f2bf(w);
        int off = (j0 + jj) * R + r0 + rr;
        dh[off] = hi;
        dl[off] = f2bf(w - bf2f(hi));
    }
}

// ---------------------------------------------------------------------------
// K1: aux MLPs via split-bf16 MFMA (validated in R7).
// ---------------------------------------------------------------------------
__global__ __launch_bounds__(256) void auxm_kernel(
    const float* __restrict__ xs,
    const unsigned short* __restrict__ W1h, const unsigned short* __restrict__ W1l,
    const float* __restrict__ b1,
    const unsigned short* __restrict__ W2h, const unsigned short* __restrict__ W2l,
    const float* __restrict__ b2,
    const float* __restrict__ W3,
    float* __restrict__ a_ws, float* __restrict__ th_ws)
{
    const int k   = blockIdx.x >> 4;
    const int n0  = (blockIdx.x & 15) << 6;
    const int tid = threadIdx.x;
    const int wv  = tid >> 6;
    const int ln  = tid & 63;
    const int lr  = ln & 15;
    const int g   = ln >> 4;
    const int cb  = wv * 32;

    __shared__ unsigned short x0h[64][40];
    __shared__ unsigned short x0l[64][40];
    __shared__ unsigned short h1h[64][136];
    __shared__ unsigned short h1l[64][136];
    __shared__ float          p3[256];

    for (int i = tid; i < 512; i += 256) {
        int r = i >> 3, qd = i & 7;
        float4 v = *(const float4*)&xs[(size_t)(n0 + r) * (T_SEQ * DIMX) + qd * 4];
        short4 hs, ls;
        float vv[4] = {v.x, v.y, v.z, v.w};
        short* hp = (short*)&hs; short* lp = (short*)&ls;
        #pragma unroll
        for (int u = 0; u < 4; ++u) {
            unsigned short hi = f2bf(vv[u]);
            hp[u] = (short)hi;
            lp[u] = (short)f2bf(vv[u] - bf2f(hi));
        }
        *(short4*)&x0h[r][qd * 4] = hs;
        *(short4*)&x0l[r][qd * 4] = ls;
    }
    __syncthreads();

    // ---- layer 1 ----
    {
        const unsigned short* W1hk = W1h + (size_t)k * 4096;
        const unsigned short* W1lk = W1l + (size_t)k * 4096;
        bf16x8 bh[2], bl[2];
        #pragma unroll
        for (int ct = 0; ct < 2; ++ct) {
            int off = (cb + ct * 16 + lr) * 32 + g * 8;
            bh[ct] = *(const bf16x8*)&W1hk[off];
            bl[ct] = *(const bf16x8*)&W1lk[off];
        }
        f32x4 acc[4][2];
        #pragma unroll
        for (int rt = 0; rt < 4; ++rt) {
            bf16x8 ah = *(const bf16x8*)&x0h[rt * 16 + lr][g * 8];
            bf16x8 al = *(const bf16x8*)&x0l[rt * 16 + lr][g * 8];
            #pragma unroll
            for (int ct = 0; ct < 2; ++ct) {
                f32x4 z = {0.f, 0.f, 0.f, 0.f};
                z = mfma16(ah, bl[ct], z);
                z = mfma16(al, bh[ct], z);
                acc[rt][ct] = mfma16(ah, bh[ct], z);
            }
        }
        #pragma unroll
        for (int ct = 0; ct < 2; ++ct) {
            const int col = cb + ct * 16 + lr;
            const float bb = b1[k * 128 + col];
            #pragma unroll
            for (int rt = 0; rt < 4; ++rt)
                #pragma unroll
                for (int i = 0; i < 4; ++i) {
                    float h = fmaxf(acc[rt][ct][i] + bb, 0.f);
                    unsigned short hi = f2bf(h);
                    int row = rt * 16 + g * 4 + i;
                    h1h[row][col] = hi;
                    h1l[row][col] = f2bf(h - bf2f(hi));
                }
        }
    }
    __syncthreads();

    // ---- layer 2 ----
    {
        const unsigned short* W2hk = W2h + (size_t)k * 16384;
        const unsigned short* W2lk = W2l + (size_t)k * 16384;
        f32x4 acc[4][2];
        #pragma unroll
        for (int rt = 0; rt < 4; ++rt)
            #pragma unroll
            for (int ct = 0; ct < 2; ++ct) acc[rt][ct] = (f32x4){0.f,0.f,0.f,0.f};

        #pragma unroll
        for (int kk = 0; kk < 4; ++kk) {
            bf16x8 bh[2], bl[2], ah[4], al[4];
            #pragma unroll
            for (int ct = 0; ct < 2; ++ct) {
                int off = (cb + ct * 16 + lr) * 128 + kk * 32 + g * 8;
                bh[ct] = *(const bf16x8*)&W2hk[off];
                bl[ct] = *(const bf16x8*)&W2lk[off];
            }
            #pragma unroll
            for (int rt = 0; rt < 4; ++rt) {
                ah[rt] = *(const bf16x8*)&h1h[rt * 16 + lr][kk * 32 + g * 8];
                al[rt] = *(const bf16x8*)&h1l[rt * 16 + lr][kk * 32 + g * 8];
            }
            #pragma unroll
            for (int rt = 0; rt < 4; ++rt)
                #pragma unroll
                for (int ct = 0; ct < 2; ++ct) {
                    f32x4 z = acc[rt][ct];
                    z = mfma16(ah[rt], bl[ct], z);
                    z = mfma16(al[rt], bh[ct], z);
                    acc[rt][ct] = mfma16(ah[rt], bh[ct], z);
                }
        }
        __syncthreads();
        #pragma unroll
        for (int ct = 0; ct < 2; ++ct) {
            const int col = cb + ct * 16 + lr;
            const float bb = b2[k * 128 + col];
            #pragma unroll
            for (int rt = 0; rt < 4; ++rt)
                #pragma unroll
                for (int i = 0; i < 4; ++i) {
                    float h = fmaxf(acc[rt][ct][i] + bb, 0.f);
                    unsigned short hi = f2bf(h);
                    int row = rt * 16 + g * 4 + i;
                    h1h[row][col] = hi;
                    h1l[row][col] = f2bf(h - bf2f(hi));
                }
        }
    }
    __syncthreads();

    // ---- layer 3 ----
    {
        const int hh = tid >> 7, r = tid & 127, n = r >> 1, o = r & 1;
        const float* W3k = W3 + (size_t)k * (AUXH * 2);
        float s = 0.f;
        #pragma unroll
        for (int h8 = hh * 64; h8 < hh * 64 + 64; h8 += 8) {
            bf16x8 vh = *(const bf16x8*)&h1h[n][h8];
            bf16x8 vl = *(const bf16x8*)&h1l[n][h8];
            #pragma unroll
            for (int u = 0; u < 8; ++u) {
                float hv = bf2f((unsigned short)vh[u]) + bf2f((unsigned short)vl[u]);
                s += hv * W3k[(h8 + u) * 2 + o];
            }
        }
        p3[tid] = s;
    }
    __syncthreads();
    if (tid < 128) {
        const int n = tid >> 1, o = tid & 1;
        float v = (p3[tid] + p3[tid + 128]) * DT;
        float* dst = o ? th_ws : a_ws;
        dst[(size_t)(n0 + n) * NAUX + k] = v;
    }
}

// ---------------------------------------------------------------------------
// K2: encoder via bf16 MFMA. NEW epilogue: acc -> LDS (reusing Hs) -> fully
// coalesced float4 row stores (whole 288-float rows, xs columns folded in).
// ---------------------------------------------------------------------------
__global__ __launch_bounds__(256) void encm_kernel(
    const float* __restrict__ xs,
    const unsigned short* __restrict__ W1T, const float* __restrict__ b1,
    const unsigned short* __restrict__ W2T, const float* __restrict__ b2,
    const unsigned short* __restrict__ W3T,
    float* __restrict__ y)
{
    __shared__ float          Xf[64 * 36];
    __shared__ unsigned short Hs[64 * 264];

    const int tid = threadIdx.x;
    const int wv  = tid >> 6;
    const int ln  = tid & 63;
    const int lr  = ln & 15;
    const int g   = ln >> 4;
    const int cb  = wv * 64;
    const size_t row0 = (size_t)blockIdx.x * 64;

    {
        const float4* src = (const float4*)(xs + row0 * DIMX);
        for (int i = tid; i < 512; i += 256) {
            int r = i >> 3, q = i & 7;
            *(float4*)&Xf[r * 36 + q * 4] = src[i];
        }
    }
    __syncthreads();

    // layer 1 (K=32)
    {
        f32x4 acc[4][4];
        bf16x8 bfr[4], afr[4];
        #pragma unroll
        for (int ct = 0; ct < 4; ++ct)
            bfr[ct] = *(const bf16x8*)&W1T[(cb + ct * 16 + lr) * 32 + g * 8];
        #pragma unroll
        for (int rt = 0; rt < 4; ++rt) {
            const float* xp = &Xf[(rt * 16 + lr) * 36 + g * 8];
            float4 u = *(const float4*)xp;
            float4 v = *(const float4*)(xp + 4);
            bf16x8 t;
            t[0]=(short)f2bf(u.x); t[1]=(short)f2bf(u.y); t[2]=(short)f2bf(u.z); t[3]=(short)f2bf(u.w);
            t[4]=(short)f2bf(v.x); t[5]=(short)f2bf(v.y); t[6]=(short)f2bf(v.z); t[7]=(short)f2bf(v.w);
            afr[rt] = t;
        }
        #pragma unroll
        for (int rt = 0; rt < 4; ++rt)
            #pragma unroll
            for (int ct = 0; ct < 4; ++ct) {
                f32x4 z = {0.f, 0.f, 0.f, 0.f};
                acc[rt][ct] = mfma16(afr[rt], bfr[ct], z);
            }
        #pragma unroll
        for (int ct = 0; ct < 4; ++ct) {
            const float bb = b1[cb + ct * 16 + lr];
            #pragma unroll
            for (int rt = 0; rt < 4; ++rt)
                #pragma unroll
                for (int i = 0; i < 4; ++i) {
                    float h = fmaxf(acc[rt][ct][i] + bb, 0.f);
                    Hs[(rt * 16 + g * 4 + i) * 264 + cb + ct * 16 + lr] = f2bf(h);
                }
        }
    }
    __syncthreads();

    int wrow[4], hoff[4];
    #pragma unroll
    for (int ct = 0; ct < 4; ++ct) wrow[ct] = (cb + ct * 16 + lr) * 256 + g * 8;
    #pragma unroll
    for (int rt = 0; rt < 4; ++rt) hoff[rt] = (rt * 16 + lr) * 264 + g * 8;

    // layer 2 (K=256)
    {
        f32x4 acc[4][4];
        #pragma unroll
        for (int rt = 0; rt < 4; ++rt)
            #pragma unroll
            for (int ct = 0; ct < 4; ++ct) acc[rt][ct] = (f32x4){0.f,0.f,0.f,0.f};
        #pragma unroll 2
        for (int kk = 0; kk < 8; ++kk) {
            bf16x8 bfr[4], afr[4];
            #pragma unroll
            for (int ct = 0; ct < 4; ++ct)
                bfr[ct] = *(const bf16x8*)&W2T[wrow[ct] + kk * 32];
            #pragma unroll
            for (int rt = 0; rt < 4; ++rt)
                afr[rt] = *(const bf16x8*)&Hs[hoff[rt] + kk * 32];
            #pragma unroll
            for (int rt = 0; rt < 4; ++rt)
                #pragma unroll
                for (int ct = 0; ct < 4; ++ct)
                    acc[rt][ct] = mfma16(afr[rt], bfr[ct], acc[rt][ct]);
        }
        __syncthreads();
        #pragma unroll
        for (int ct = 0; ct < 4; ++ct) {
            const float bb = b2[cb + ct * 16 + lr];
            #pragma unroll
            for (int rt = 0; rt < 4; ++rt)
                #pragma unroll
                for (int i = 0; i < 4; ++i) {
                    float h = fmaxf(acc[rt][ct][i] + bb, 0.f);
                    Hs[(rt * 16 + g * 4 + i) * 264 + cb + ct * 16 + lr] = f2bf(h);
                }
        }
    }
    __syncthreads();

    // layer 3 (K=256) — accumulate, then coalesced two-pass store
    {
        f32x4 acc[4][4];
        #pragma unroll
        for (int rt = 0; rt < 4; ++rt)
            #pragma unroll
            for (int ct = 0; ct < 4; ++ct) acc[rt][ct] = (f32x4){0.f,0.f,0.f,0.f};
        #pragma unroll 2
        for (int kk = 0; kk < 8; ++kk) {
            bf16x8 bfr[4], afr[4];
            #pragma unroll
            for (int ct = 0; ct < 4; ++ct)
                bfr[ct] = *(const bf16x8*)&W3T[wrow[ct] + kk * 32];
            #pragma unroll
            for (int rt = 0; rt < 4; ++rt)
                afr[rt] = *(const bf16x8*)&Hs[hoff[rt] + kk * 32];
            #pragma unroll
            for (int rt = 0; rt < 4; ++rt)
                #pragma unroll
                for (int ct = 0; ct < 4; ++ct)
                    acc[rt][ct] = mfma16(afr[rt], bfr[ct], acc[rt][ct]);
        }
        __syncthreads();   // all Hs reads done — safe to reuse as float stage

        float* HsF = (float*)Hs;       // 32 rows x 264 floats = exactly |Hs|
        const int r  = tid >> 3;       // 0..31   (store row within pass)
        const int ce = tid & 7;        // 0..7    (col-thread)

        #pragma unroll
        for (int p = 0; p < 2; ++p) {
            #pragma unroll
            for (int rt = 2 * p; rt < 2 * p + 2; ++rt)
                #pragma unroll
                for (int ct = 0; ct < 4; ++ct)
                    #pragma unroll
                    for (int i = 0; i < 4; ++i)
                        HsF[((rt - 2 * p) * 16 + g * 4 + i) * 264 + cb + ct * 16 + lr]
                            = acc[rt][ct][i];
            __syncthreads();
            // full 288-float rows: f4 0..7 from Xf (xs), 8..71 from HsF (e)
            const int rloc = p * 32 + r;
            float* dstrow = &y[(row0 + rloc) * OUTC];
            #pragma unroll
            for (int j = 0; j < 9; ++j) {
                int f4 = j * 8 + ce;           // 0..71, interleaved (bank-safe)
                float4 v;
                if (f4 < 8) v = *(const float4*)&Xf[rloc * 36 + f4 * 4];
                else        v = *(const float4*)&HsF[r * 264 + (f4 - 8) * 4];
                *(float4*)&dstrow[f4 * 4] = v;
            }
            __syncthreads();
        }
    }
}

// ---------------------------------------------------------------------------
// K3: fp32 encoder for the 1024 t=0 rows. NEW: 1 row/block, 1024 blocks
// (4 blocks/CU, 16 waves/CU — was 1 block/CU).
// ---------------------------------------------------------------------------
__global__ __launch_bounds__(256) void enc0_kernel(
    const float* __restrict__ xs,
    const float* __restrict__ W1, const float* __restrict__ b1,
    const float* __restrict__ W2, const float* __restrict__ b2,
    const float* __restrict__ W3,
    float* __restrict__ y)
{
    __shared__ float Xs[32];
    __shared__ float Hsf[256];
    const int tid = threadIdx.x;
    const int c   = tid;
    const int n   = blockIdx.x;

    if (tid < 32) Xs[tid] = xs[(size_t)n * (T_SEQ * DIMX) + tid];
    __syncthreads();

    // L1 (K=32)
    float a = b1[c];
    #pragma unroll 8
    for (int d = 0; d < 32; ++d)
        a += Xs[d] * W1[d * ENCH + c];
    Hsf[c] = fmaxf(a, 0.f);
    __syncthreads();

    // L2 (K=256)
    float a2 = b2[c];
    #pragma unroll 8
    for (int h = 0; h < 256; ++h)
        a2 += Hsf[h] * W2[h * ENCH + c];
    __syncthreads();
    Hsf[c] = fmaxf(a2, 0.f);
    __syncthreads();

    // L3 (K=256)
    float a3 = 0.f;
    #pragma unroll 8
    for (int h = 0; h < 256; ++h)
        a3 += Hsf[h] * W3[h * LDIM + c];
    y[((size_t)n * T_SEQ) * OUTC + DIMX + c] = a3;
}

// ---------------------------------------------------------------------------
// K4: scan3b — as R7's proven scan3, with C_W loads hoisted (l-outer, both
// t's share each cw float4). Rotation scheme unchanged (conflict-free).
// ---------------------------------------------------------------------------
__global__ __launch_bounds__(256) void scan3_kernel(
    const float* __restrict__ xs,
    const float* __restrict__ a_ws, const float* __restrict__ th_ws,
    const float* __restrict__ cwt,   // C_W^T [32d][256l], fp32
    const float* __restrict__ y,
    float* __restrict__ yp)
{
    __shared__ float ys_lds[16][256];   // 16 KB

    const int n = blockIdx.x >> 2;
    const int q = blockIdx.x & 3;
    const int e = threadIdx.x;
    const int k = e >> 1;

    const float* yrow0 = y + (size_t)n * T_SEQ * OUTC + DIMX;
    float2 y0 = *(const float2*)&yrow0[e & ~1];
    const float a  = a_ws [n * NAUX + k];
    const float th = th_ws[n * NAUX + k];

    const float m = expf(a);
    float ss, cc; sincosf(th, &ss, &cc);
    const float zr = m * cc, zi = m * ss;

    float pr = zr, pi = zi;
    #pragma unroll
    for (int s2 = 0; s2 < 4; ++s2) {
        float nr = pr * pr - pi * pi;
        pi = 2.f * pr * pi; pr = nr;
    }
    float wr = 1.f, wi = 0.f;
    for (int j = 0; j < q; ++j) {
        float nr = wr * pr - wi * pi;
        wi = wr * pi + wi * pr; wr = nr;
    }

    const bool imag = e & 1;
    float* ypn = yp + (size_t)n * T_SEQ * OUTC;

    #pragma unroll 4
    for (int tl = 0; tl < 16; ++tl) {
        const int t = q * 16 + tl;
        float val = imag ? (y0.x * wi + y0.y * wr)
                         : (y0.x * wr - y0.y * wi);
        ypn[(size_t)t * OUTC + DIMX + e] = val;
        ys_lds[tl][(e + ((tl >> 1) & 7) * 4) & 255] = val;
        float nwr = wr * zr - wi * zi;
        wi = wr * zi + wi * zr;
        wr = nwr;
    }
    __syncthreads();

    const int d   = e >> 3;
    const int tg  = e & 7;
    const int tl0 = tg * 2, tl1 = tl0 + 1;
    const float* cwd = cwt + d * 256;
    const int rot = tg * 4;

    float s0 = 0.f, s1 = 0.f;
    #pragma unroll 8
    for (int l = 0; l < 256; l += 4) {
        const int c0 = (l + rot) & 255;
        float4 wv = *(const float4*)&cwd[l];
        float4 ya = *(const float4*)&ys_lds[tl0][c0];
        float4 yb = *(const float4*)&ys_lds[tl1][c0];
        s0 += ya.x * wv.x + ya.y * wv.y + ya.z * wv.z + ya.w * wv.w;
        s1 += yb.x * wv.x + yb.y * wv.y + yb.z * wv.z + yb.w * wv.w;
    }
    const int t0 = q * 16 + tl0;
    const int t1 = q * 16 + tl1;
    float o0 = (t0 == 0) ? xs[(size_t)n * T_SEQ * DIMX + d] : s0;
    ypn[(size_t)t0 * OUTC + d] = o0;
    ypn[(size_t)t1 * OUTC + d] = s1;     // t1 = t0+1 is never 0
}

// ---------------------------------------------------------------------------
extern "C" void kernel_launch(void* const* d_in, const int* in_sizes, int n_in,
                              void* d_out, int out_size, void* d_ws, size_t ws_size,
                              hipStream_t stream)
{
    const float* xs   = (const float*)d_in[0];
    const float* eW1  = (const float*)d_in[1];
    const float* eb1  = (const float*)d_in[2];
    const float* eW2  = (const float*)d_in[3];
    const float* eb2  = (const float*)d_in[4];
    const float* eW3  = (const float*)d_in[5];
    const float* aW1  = (const float*)d_in[6];
    const float* ab1  = (const float*)d_in[7];
    const float* aW2  = (const float*)d_in[8];
    const float* ab2  = (const float*)d_in[9];
    const float* aW3  = (const float*)d_in[10];
    const float* C_W  = (const float*)d_in[11];

    float* y  = (float*)d_out;
    float* yp = y + (size_t)N_SEQ * T_SEQ * OUTC;

    // workspace layout (identical to R7)
    float* a_ws  = (float*)d_ws;
    float* th_ws = a_ws + (size_t)N_SEQ * NAUX;
    unsigned short* encw = (unsigned short*)(th_ws + (size_t)N_SEQ * NAUX);
    unsigned short* W1T = encw;
    unsigned short* W2T = encw + 8192;
    unsigned short* W3T = encw + 8192 + 65536;
    unsigned short* a1h = encw + CV_ENC;
    unsigned short* a1l = a1h + 524288;
    unsigned short* a2h = a1l + 524288;
    unsigned short* a2l = a2h + 2097152;
    float* cwt = (float*)(a2l + 2097152);

    prep_kernel<<<PREP_CONV_BLOCKS + 2560, 256, 0, stream>>>(
        eW1, eW2, eW3, C_W, aW1, aW2, encw, cwt, a1h, a1l, a2h, a2l);
    auxm_kernel <<<128 * 16, 256, 0, stream>>>(
        xs, a1h, a1l, ab1, a2h, a2l, ab2, aW3, a_ws, th_ws);
    encm_kernel <<<N_SEQ * T_SEQ / 64, 256, 0, stream>>>(xs, W1T, eb1, W2T, eb2, W3T, y);
    enc0_kernel <<<N_SEQ, 256, 0, stream>>>(xs, eW1, eb1, eW2, eb2, eW3, y);
    scan3_kernel<<<N_SEQ * 4, 256, 0, stream>>>(xs, a_ws, th_ws, cwt, y, yp);
}